// Round 1
// baseline (1557.994 us; speedup 1.0000x reference)
//
#include <hip/hip_runtime.h>
#include <math.h>

#define Nn 64
#define Cn 64
#define Tn 64
#define Vn 25
#define Sn 8
#define ICn 8
#define Wn 3
#define WVn 75

// ---------------------------------------------------------------------------
// K1: per (n,c) reductions over x rows:
//   red[(n*C+c)*4 + 0] = sum_{t,v} xp          (Rsum)
//   red[...+1]         = sum_v xp[t=0]          (R0)
//   red[...+2]         = sum_v xp[t=63]         (R63)
//   red[...+3]         = sum_{t,u} xp * ga_rowsum[u]   (Xga)
// x layout: (N,C,V,T)
// ---------------------------------------------------------------------------
__global__ __launch_bounds__(64) void k_red(const float* __restrict__ x,
                                            const float* __restrict__ ga,
                                            float* __restrict__ red) {
    const int c = blockIdx.x, n = blockIdx.y;
    const int lane = threadIdx.x;
    float rs = 0.f, r0 = 0.f, r63 = 0.f, xg = 0.f;
    if (lane < Vn) {
        const float* row = x + ((size_t)(n * Cn + c) * Vn + lane) * Tn;
        float g = 0.f;
        for (int j = 0; j < Vn; ++j) g += ga[lane * Vn + j];
        for (int t = 0; t < Tn; ++t) rs += row[t];
        r0 = row[0];
        r63 = row[Tn - 1];
        xg = rs * g;
    }
    for (int off = 32; off > 0; off >>= 1) {
        rs += __shfl_down(rs, off);
        r0 += __shfl_down(r0, off);
        r63 += __shfl_down(r63, off);
        xg += __shfl_down(xg, off);
    }
    if (lane == 0) {
        float* p = red + (size_t)(n * Cn + c) * 4;
        p[0] = rs; p[1] = r0; p[2] = r63; p[3] = xg;
    }
}

// ---------------------------------------------------------------------------
// K1b: gate[n,s,w] = sigmoid( (sumD2[n,s] - sumUpf[n,s,w]) / 12800 )
//   sumD2[n,s]  = sum_cc ( sum_c Xga[n,c]*diff_w[s*8+cc,c] + 1600*diff_b )
//   sumUpf[n,s,0] = sum_cc (Rsum - R63);  w=1: Rsum;  w=2: (Rsum - R0)
// ---------------------------------------------------------------------------
__global__ __launch_bounds__(64) void k_gate(const float* __restrict__ red,
                                             const float* __restrict__ diff_w,
                                             const float* __restrict__ diff_b,
                                             float* __restrict__ gate) {
    const int n = blockIdx.x;
    const int s = threadIdx.x;
    if (s >= Sn) return;
    float sumd2 = 0.f, rsum = 0.f, rr0 = 0.f, rr63 = 0.f;
    for (int cc = 0; cc < ICn; ++cc) {
        const int oc = s * ICn + cc;
        float a = 0.f;
        for (int c = 0; c < Cn; ++c)
            a += red[(n * Cn + c) * 4 + 3] * diff_w[oc * Cn + c];
        sumd2 += a + 1600.f * diff_b[oc];
        rsum += red[(n * Cn + oc) * 4 + 0];
        rr0  += red[(n * Cn + oc) * 4 + 1];
        rr63 += red[(n * Cn + oc) * 4 + 2];
    }
    const float inv = 1.f / 12800.f;
    float m0 = (sumd2 - (rsum - rr63)) * inv;
    float m1 = (sumd2 - rsum) * inv;
    float m2 = (sumd2 - (rsum - rr0)) * inv;
    float* gp = gate + (n * Sn + s) * Wn;
    gp[0] = 1.f / (1.f + expf(-m0));
    gp[1] = 1.f / (1.f + expf(-m1));
    gp[2] = 1.f / (1.f + expf(-m2));
}

// ---------------------------------------------------------------------------
// K2: attention per (s, n).
//   Projects each temporal row of xp once (rotating 3-slot buffer):
//     prot[slot][cc][v] = sum_c xp[n,c,row,v]*inup_w[s*8+cc,c] + inup_b  (q)
//     prok[slot][cc][v] = sum_c xp[n,c,row,v]*in_w  [s*8+cc,c] + in_b    (k)
//   Zero-padded rows (t=-1, t=64) hold bias only (matches reference pad).
//   attacc[u,v] = sum_t sum_cc q[cc, row(t + u/25 - 1), u%25] * k[cc,row t,v]
//   Then: /512, mask by graph[s][u%25][v], softmax over v, *gate[n,s,u%3], +att0.
// ---------------------------------------------------------------------------
__global__ __launch_bounds__(256) void k_att(
    const float* __restrict__ x, const float* __restrict__ graph,
    const float* __restrict__ in_w, const float* __restrict__ in_b,
    const float* __restrict__ inup_w, const float* __restrict__ inup_b,
    const float* __restrict__ att0, const float* __restrict__ gate,
    float* __restrict__ att_out) {
    const int s = blockIdx.x, n = blockIdx.y;
    const int tid = threadIdx.x;

    __shared__ float xq[1600];            // [c4][v][4] transposed row
    __shared__ float wqs[ICn * Cn];       // inup_w rows for this s
    __shared__ float wks[ICn * Cn];       // in_w rows
    __shared__ float prot[3][ICn * Vn];
    __shared__ float prok[3][ICn * Vn];
    __shared__ float qb[ICn], kb[ICn];
    __shared__ float attacc[WVn * Vn];

    for (int i = tid; i < ICn * Cn; i += 256) {
        int cc = i >> 6, c = i & 63;
        wqs[i] = inup_w[(s * ICn + cc) * Cn + c];
        wks[i] = in_w[(s * ICn + cc) * Cn + c];
    }
    if (tid < ICn) {
        qb[tid] = inup_b[s * ICn + tid];
        kb[tid] = in_b[s * ICn + tid];
    }
    __syncthreads();
    if (tid < ICn * Vn) {  // row -1 -> slot 0: bias only
        int cc = tid / Vn;
        prot[0][tid] = qb[cc];
        prok[0][tid] = kb[cc];
    }

    const int ut = tid / 13, vt = tid % 13;  // 4u x 2v accumulator tile
    const bool cvalid = (tid < 247);
    float acc[4][2];
#pragma unroll
    for (int a = 0; a < 4; ++a) { acc[a][0] = 0.f; acc[a][1] = 0.f; }

    for (int tt = -1; tt < Tn; ++tt) {
        const int rr = tt + 1;  // row being loaded/projected this iter
        // ---- A: load row rr (transposed c-fastest-in-float4)
        for (int i = tid; i < 1600; i += 256) {
            int c = i & 63, v = i >> 6;
            float val = (rr < Tn) ? x[((size_t)(n * Cn + c) * Vn + v) * Tn + rr] : 0.f;
            xq[((c >> 2) * Vn + v) * 4 + (c & 3)] = val;
        }
        __syncthreads();
        // ---- B: project row rr into slot (tt+2)%3
        const int slot_new = (tt + 2) % 3;
        if (tid < 200) {
            int cc = tid / Vn, vv = tid % Vn;
            float aq = qb[cc], ak = kb[cc];
            const float4* wq4 = (const float4*)&wqs[cc * 64];
            const float4* wk4 = (const float4*)&wks[cc * 64];
#pragma unroll 4
            for (int c4 = 0; c4 < 16; ++c4) {
                float4 xv = *(const float4*)&xq[(c4 * Vn + vv) * 4];
                float4 wq = wq4[c4], wk = wk4[c4];
                aq += xv.x * wq.x + xv.y * wq.y + xv.z * wq.z + xv.w * wq.w;
                ak += xv.x * wk.x + xv.y * wk.y + xv.z * wk.z + xv.w * wk.w;
            }
            prot[slot_new][cc * Vn + vv] = aq;
            prok[slot_new][cc * Vn + vv] = ak;
        }
        __syncthreads();
        // ---- C: accumulate att for t = tt (k row = slot (tt+1)%3)
        if (tt >= 0 && cvalid) {
            const int s0 = tt % 3, s1 = (tt + 1) % 3, s2 = (tt + 2) % 3;
            float kv0[ICn], kv1[ICn];
            const int v0 = vt * 2;
#pragma unroll
            for (int cc = 0; cc < ICn; ++cc) {
                kv0[cc] = prok[s1][cc * Vn + v0];
                kv1[cc] = (v0 + 1 < Vn) ? prok[s1][cc * Vn + v0 + 1] : 0.f;
            }
#pragma unroll
            for (int du = 0; du < 4; ++du) {
                int u = ut * 4 + du;
                if (u < WVn) {
                    int w = u / Vn, uu = u % Vn;
                    int sl = (w == 0) ? s0 : ((w == 1) ? s1 : s2);
#pragma unroll
                    for (int cc = 0; cc < ICn; ++cc) {
                        float qv = prot[sl][cc * Vn + uu];
                        acc[du][0] += qv * kv0[cc];
                        acc[du][1] += qv * kv1[cc];
                    }
                }
            }
        }
    }
    // ---- write acc tile to LDS
    if (cvalid) {
#pragma unroll
        for (int du = 0; du < 4; ++du) {
            int u = ut * 4 + du;
            if (u < WVn) {
#pragma unroll
                for (int dv = 0; dv < 2; ++dv) {
                    int v = vt * 2 + dv;
                    if (v < Vn) attacc[u * Vn + v] = acc[du][dv];
                }
            }
        }
    }
    __syncthreads();
    // ---- masked softmax over v, * gate[n,s,u%3], + att0
    for (int u = tid; u < WVn; u += 256) {
        const int u0 = u % Vn;
        const float* gr = graph + (s * Vn + u0) * Vn;
        float av[Vn];
        float mx = -1e30f;
#pragma unroll
        for (int v = 0; v < Vn; ++v) {
            float a = attacc[u * Vn + v] * (1.f / 512.f);
            av[v] = (gr[v] > 0.f) ? a : -1e30f;
            mx = fmaxf(mx, av[v]);
        }
        float ssum = 0.f;
#pragma unroll
        for (int v = 0; v < Vn; ++v) {
            float e = (av[v] > -1e29f) ? expf(av[v] - mx) : 0.f;
            av[v] = e;
            ssum += e;
        }
        const float g = gate[(n * Sn + s) * Wn + (u % Wn)];
        const float sc = g / ssum;
        float* op = att_out + ((size_t)(n * Sn + s) * WVn + u) * Vn;
        const float* a0 = att0 + (s * WVn + u) * Vn;
#pragma unroll
        for (int v = 0; v < Vn; ++v) op[v] = av[v] * sc + a0[v];
    }
}

// ---------------------------------------------------------------------------
// K3: per (t-chunk of 4, n): aggregate + out-proj + BN + leaky + ff + BN +
//     leaky + relu + transpose back to (N,C,V,T).
// Thread (o, tl): o = output channel, tl = t within chunk.
// att rows read with wave-uniform indices (scalar-load path).
// ---------------------------------------------------------------------------
__global__ __launch_bounds__(256) void k_main(
    const float* __restrict__ x, const float* __restrict__ att,
    const float* __restrict__ out_w, const float* __restrict__ out_b,
    const float* __restrict__ og, const float* __restrict__ obeta,
    const float* __restrict__ orm, const float* __restrict__ orv,
    const float* __restrict__ ff_w, const float* __restrict__ ff_b,
    const float* __restrict__ fg, const float* __restrict__ fbeta,
    const float* __restrict__ frm, const float* __restrict__ frv,
    float* __restrict__ out) {
    const int tc = blockIdx.x, n = blockIdx.y;
    const int t0 = tc * 4;
    const int tid = threadIdx.x;
    const int o = tid >> 2, tl = tid & 3;

    __shared__ float xs[6][Cn * Vn + 1];  // rows t0-1..t0+4, pad stride 1601
    __shared__ float ybuf[Cn * 4 * 28];   // [c][tl][28] (v padded to 28)

    for (int i = tid; i < 6 * 1600; i += 256) {
        int r = i / 1600, j = i % 1600;
        int c = j & 63, v = j >> 6;
        int gt = t0 + r - 1;
        xs[r][c * Vn + v] =
            (gt >= 0 && gt < Tn) ? x[((size_t)(n * Cn + c) * Vn + v) * Tn + gt] : 0.f;
    }

    float yo[28];
#pragma unroll
    for (int v = 0; v < 28; ++v) yo[v] = 0.f;
    __syncthreads();

    for (int s = 0; s < Sn; ++s) {
        // ---- y2_s[c=o][t=t0+tl][v] = sum_u upf * att_s[u,v]
        float acc[Vn];
#pragma unroll
        for (int v = 0; v < Vn; ++v) acc[v] = 0.f;
        const float* atp = att + ((size_t)(n * Sn + s) * WVn) * Vn;
        for (int w = 0; w < Wn; ++w) {
            const float* xrow = &xs[tl + w][o * Vn];
            for (int vv = 0; vv < Vn; ++vv) {
                float xv = xrow[vv];
                const float* arow = atp + (w * Vn + vv) * Vn;  // uniform -> s_load
#pragma unroll
                for (int v = 0; v < Vn; ++v) acc[v] += xv * arow[v];
            }
        }
        float* yrow = &ybuf[(o * 4 + tl) * 28];
#pragma unroll
        for (int v = 0; v < Vn; ++v) yrow[v] = acc[v];
        yrow[25] = 0.f; yrow[26] = 0.f; yrow[27] = 0.f;
        __syncthreads();
        // ---- yo[o] += out_w[o, s*64+c] * y2_s[c]
        const float4* wrow = (const float4*)(out_w + (size_t)o * (Sn * Cn) + s * Cn);
        for (int c4 = 0; c4 < 16; ++c4) {
            float4 w4 = wrow[c4];
#pragma unroll
            for (int dc = 0; dc < 4; ++dc) {
                int c = c4 * 4 + dc;
                float wv = (dc == 0) ? w4.x : (dc == 1) ? w4.y : (dc == 2) ? w4.z : w4.w;
                const float4* yr4 = (const float4*)&ybuf[(c * 4 + tl) * 28];
#pragma unroll
                for (int v4 = 0; v4 < 7; ++v4) {
                    float4 yv = yr4[v4];
                    yo[v4 * 4 + 0] += wv * yv.x;
                    yo[v4 * 4 + 1] += wv * yv.y;
                    yo[v4 * 4 + 2] += wv * yv.z;
                    yo[v4 * 4 + 3] += wv * yv.w;
                }
            }
        }
        __syncthreads();
    }

    // ---- BN(out) + leaky(x + .), stage y1 into ybuf
    const float sc_o = og[o] * rsqrtf(orv[o] + 1e-5f);
    const float sh_o = obeta[o] - orm[o] * sc_o;
    const float bo = out_b[o];
    const float* xcen = &xs[tl + 1][o * Vn];
    float xres[Vn];
    float* yrow = &ybuf[(o * 4 + tl) * 28];
#pragma unroll
    for (int v = 0; v < Vn; ++v) {
        float xv = xcen[v];
        xres[v] = xv;
        float val = (yo[v] + bo) * sc_o + sh_o;
        float y1 = xv + val;
        yrow[v] = (y1 > 0.f) ? y1 : 0.1f * y1;
    }
    yrow[25] = 0.f; yrow[26] = 0.f; yrow[27] = 0.f;
    __syncthreads();
    // ---- ff projection + BN + leaky + relu residual
    float zf[28];
#pragma unroll
    for (int v = 0; v < 28; ++v) zf[v] = 0.f;
    const float4* fw4 = (const float4*)(ff_w + o * Cn);
    for (int c4 = 0; c4 < 16; ++c4) {
        float4 w4 = fw4[c4];
#pragma unroll
        for (int dc = 0; dc < 4; ++dc) {
            int c = c4 * 4 + dc;
            float wv = (dc == 0) ? w4.x : (dc == 1) ? w4.y : (dc == 2) ? w4.z : w4.w;
            const float4* yr4 = (const float4*)&ybuf[(c * 4 + tl) * 28];
#pragma unroll
            for (int v4 = 0; v4 < 7; ++v4) {
                float4 yv = yr4[v4];
                zf[v4 * 4 + 0] += wv * yv.x;
                zf[v4 * 4 + 1] += wv * yv.y;
                zf[v4 * 4 + 2] += wv * yv.z;
                zf[v4 * 4 + 3] += wv * yv.w;
            }
        }
    }
    const float sc_f = fg[o] * rsqrtf(frv[o] + 1e-5f);
    const float sh_f = fbeta[o] - frm[o] * sc_f;
    const float bf = ff_b[o];
#pragma unroll
    for (int v = 0; v < Vn; ++v) {
        float val = (zf[v] + bf) * sc_f + sh_f;
        float y2v = xres[v] + val;
        y2v = (y2v > 0.f) ? y2v : 0.1f * y2v;
        float outv = y2v + xres[v];
        outv = (outv > 0.f) ? outv : 0.f;
        out[((size_t)(n * Cn + o) * Vn + v) * Tn + t0 + tl] = outv;
    }
}

// ---------------------------------------------------------------------------
extern "C" void kernel_launch(void* const* d_in, const int* in_sizes, int n_in,
                              void* d_out, int out_size, void* d_ws, size_t ws_size,
                              hipStream_t stream) {
    const float* x       = (const float*)d_in[0];
    const float* graph   = (const float*)d_in[1];
    const float* graph_a = (const float*)d_in[2];
    const float* in_w    = (const float*)d_in[3];
    const float* in_b    = (const float*)d_in[4];
    const float* inup_w  = (const float*)d_in[5];
    const float* inup_b  = (const float*)d_in[6];
    const float* diff_w  = (const float*)d_in[7];
    const float* diff_b  = (const float*)d_in[8];
    const float* att0    = (const float*)d_in[9];
    const float* out_w   = (const float*)d_in[10];
    const float* out_b   = (const float*)d_in[11];
    const float* og      = (const float*)d_in[12];
    const float* obeta   = (const float*)d_in[13];
    const float* orm     = (const float*)d_in[14];
    const float* orv     = (const float*)d_in[15];
    const float* ff_w    = (const float*)d_in[16];
    const float* ff_b    = (const float*)d_in[17];
    const float* fg      = (const float*)d_in[18];
    const float* fbeta   = (const float*)d_in[19];
    const float* frm     = (const float*)d_in[20];
    const float* frv     = (const float*)d_in[21];
    float* out = (float*)d_out;

    float* ws      = (float*)d_ws;
    float* att_ws  = ws;                      // N*S*75*25 = 960000 floats
    float* red_ws  = ws + 960000;             // N*C*4     =  16384 floats
    float* gate_ws = ws + 960000 + 16384;     // N*S*3     =   1536 floats

    k_red<<<dim3(Cn, Nn), 64, 0, stream>>>(x, graph_a, red_ws);
    k_gate<<<dim3(Nn), 64, 0, stream>>>(red_ws, diff_w, diff_b, gate_ws);
    k_att<<<dim3(Sn, Nn), 256, 0, stream>>>(x, graph, in_w, in_b, inup_w, inup_b,
                                            att0, gate_ws, att_ws);
    k_main<<<dim3(Tn / 4, Nn), 256, 0, stream>>>(x, att_ws, out_w, out_b, og, obeta,
                                                 orm, orv, ff_w, ff_b, fg, fbeta,
                                                 frm, frv, out);
}

// Round 2
// 750.554 us; speedup vs baseline: 2.0758x; 2.0758x over previous
//
#include <hip/hip_runtime.h>
#include <hip/hip_bf16.h>
#include <math.h>

#define Nn 64
#define Cn 64
#define Tn 64
#define Vn 25
#define Sn 8
#define ICn 8
#define Wn 3
#define WVn 75

// ---------------------------------------------------------------------------
// K1: per (n,c) reductions over x rows (for the collapsed diff/gate branch).
// ---------------------------------------------------------------------------
__global__ __launch_bounds__(64) void k_red(const float* __restrict__ x,
                                            const float* __restrict__ ga,
                                            float* __restrict__ red) {
    const int c = blockIdx.x, n = blockIdx.y;
    const int lane = threadIdx.x;
    float rs = 0.f, r0 = 0.f, r63 = 0.f, xg = 0.f;
    if (lane < Vn) {
        const float* row = x + ((size_t)(n * Cn + c) * Vn + lane) * Tn;
        float g = 0.f;
        for (int j = 0; j < Vn; ++j) g += ga[lane * Vn + j];
        for (int t = 0; t < Tn; ++t) rs += row[t];
        r0 = row[0];
        r63 = row[Tn - 1];
        xg = rs * g;
    }
    for (int off = 32; off > 0; off >>= 1) {
        rs += __shfl_down(rs, off);
        r0 += __shfl_down(r0, off);
        r63 += __shfl_down(r63, off);
        xg += __shfl_down(xg, off);
    }
    if (lane == 0) {
        float* p = red + (size_t)(n * Cn + c) * 4;
        p[0] = rs; p[1] = r0; p[2] = r63; p[3] = xg;
    }
}

// ---------------------------------------------------------------------------
// K1b: gate[n,s,w] = sigmoid( (sumD2[n,s] - sumUpf[n,s,w]) / 12800 )
// ---------------------------------------------------------------------------
__global__ __launch_bounds__(64) void k_gate(const float* __restrict__ red,
                                             const float* __restrict__ diff_w,
                                             const float* __restrict__ diff_b,
                                             float* __restrict__ gate) {
    const int n = blockIdx.x;
    const int s = threadIdx.x;
    if (s >= Sn) return;
    float sumd2 = 0.f, rsum = 0.f, rr0 = 0.f, rr63 = 0.f;
    for (int cc = 0; cc < ICn; ++cc) {
        const int oc = s * ICn + cc;
        float a = 0.f;
        for (int c = 0; c < Cn; ++c)
            a += red[(n * Cn + c) * 4 + 3] * diff_w[oc * Cn + c];
        sumd2 += a + 1600.f * diff_b[oc];
        rsum += red[(n * Cn + oc) * 4 + 0];
        rr0  += red[(n * Cn + oc) * 4 + 1];
        rr63 += red[(n * Cn + oc) * 4 + 2];
    }
    const float inv = 1.f / 12800.f;
    float m0 = (sumd2 - (rsum - rr63)) * inv;
    float m1 = (sumd2 - rsum) * inv;
    float m2 = (sumd2 - (rsum - rr0)) * inv;
    float* gp = gate + (n * Sn + s) * Wn;
    gp[0] = 1.f / (1.f + expf(-m0));
    gp[1] = 1.f / (1.f + expf(-m1));
    gp[2] = 1.f / (1.f + expf(-m2));
}

// ---------------------------------------------------------------------------
// K_proj: pk[n][o][v][t] = sum_c in_w[o][c]*x[n][c][v][t] + in_b[o]  (bf16)
//         pq[.........] same with inup_w/inup_b.
// Block (v, n); x read along contiguous t (coalesced, read exactly once).
// ---------------------------------------------------------------------------
__global__ __launch_bounds__(256) void k_proj(
    const float* __restrict__ x,
    const float* __restrict__ in_w, const float* __restrict__ in_b,
    const float* __restrict__ inup_w, const float* __restrict__ inup_b,
    __hip_bfloat16* __restrict__ pk, __hip_bfloat16* __restrict__ pq) {
    const int v = blockIdx.x, n = blockIdx.y;
    const int tid = threadIdx.x;
    __shared__ float xs[64 * 65];   // [c][t] pad 65 (2-way max, free)
    __shared__ float wk[64 * 65];   // [o][c] pad 65 -> bank (o+c)%32
    __shared__ float wq[64 * 65];

    for (int i = tid; i < 4096; i += 256) {
        int o = i >> 6, c = i & 63;
        wk[o * 65 + c] = in_w[i];
        wq[o * 65 + c] = inup_w[i];
    }
    for (int i = tid; i < 4096; i += 256) {
        int c = i >> 6, t = i & 63;
        xs[c * 65 + t] = x[((size_t)(n * Cn + c) * Vn + v) * Tn + t];
    }
    __syncthreads();

    const int o = tid >> 2, tq = tid & 3;
    float ak[16], aq[16];
#pragma unroll
    for (int t = 0; t < 16; ++t) { ak[t] = 0.f; aq[t] = 0.f; }
    for (int c = 0; c < 64; ++c) {
        float wkc = wk[o * 65 + c], wqc = wq[o * 65 + c];
        const float* xr = &xs[c * 65 + tq * 16];
#pragma unroll
        for (int t = 0; t < 16; ++t) {
            float xv = xr[t];
            ak[t] += wkc * xv;
            aq[t] += wqc * xv;
        }
    }
    const float bk = in_b[o], bq = inup_b[o];
    const size_t base = ((size_t)(n * Cn + o) * Vn + v) * Tn + tq * 16;
#pragma unroll
    for (int t = 0; t < 16; ++t) {
        pk[base + t] = __float2bfloat16(ak[t] + bk);
        pq[base + t] = __float2bfloat16(aq[t] + bq);
    }
}

// ---------------------------------------------------------------------------
// K_att2: partial attention logits for t-half h.
// LDS slabs in flat (cc, slot) layout, slot in [0,34): slot<->t_glob=h*32-1+slot.
// k zero-padded at slot 0/33 so the flat shifted dot
//   att[u,v] = sum_j qs[uu][j + w-1] * ks[v][j]
// is exact (cross-boundary terms multiply k=0). q pad slots hold inup bias
// (reference zero-pad rows project to bias). Shift folded into base pointers.
// ---------------------------------------------------------------------------
#define ROWL 273   // 8*34 + 1 pad (odd stride -> spread banks)
#define JTOT 272   // 8*34
__global__ __launch_bounds__(256) void k_att2(
    const __hip_bfloat16* __restrict__ pq, const __hip_bfloat16* __restrict__ pk,
    const float* __restrict__ inup_b, float* __restrict__ att_part) {
    const int s = blockIdx.x, n = blockIdx.y, h = blockIdx.z;
    const int tid = threadIdx.x;
    __shared__ float slab[26 * ROWL + 25 * ROWL];  // ks[26 rows] then qs[25 rows]
    float* ksl = slab;
    float* qsl = slab + 26 * ROWL;

    for (int i = tid; i < 51 * ROWL; i += 256) slab[i] = 0.f;
    __syncthreads();

    // fill k: 8cc x 25v x 32tt  (slots 1..32; 0/33 stay zero)
    for (int i = tid; i < 6400; i += 256) {
        int tt = i & 31, v = (i >> 5) % 25, cc = i / 800;
        float val = __bfloat162float(
            pk[((size_t)(n * Cn + s * ICn + cc) * Vn + v) * Tn + h * 32 + tt]);
        ksl[v * ROWL + cc * 34 + 1 + tt] = val;
    }
    // fill q: 8cc x 25uu x 34slot (out-of-range t -> bias)
    for (int i = tid; i < 6800; i += 256) {
        int slot = i % 34, uu = (i / 34) % 25, cc = i / 850;
        int tg = h * 32 - 1 + slot;
        int ch = s * ICn + cc;
        float val = (tg >= 0 && tg < Tn)
            ? __bfloat162float(pq[((size_t)(n * Cn + ch) * Vn + uu) * Tn + tg])
            : inup_b[ch];
        qsl[uu * ROWL + cc * 34 + slot] = val;
    }
    __syncthreads();

    if (tid < 247) {
        const int ut = tid / 13, vt = tid % 13;
        const int v0 = vt * 2;
        const float* kp0 = &ksl[v0 * ROWL];
        const float* kp1 = &ksl[(v0 + 1) * ROWL];  // row 25 = zero pad when v0=24
        const float* qp[4];
#pragma unroll
        for (int du = 0; du < 4; ++du) {
            int u = ut * 4 + du;
            int w = (u < WVn) ? u / Vn : 1;
            int uu = (u < WVn) ? u % Vn : 0;
            qp[du] = &qsl[uu * ROWL + (w - 1)];  // qsl[-1] = ksl zero row tail
        }
        float acc[4][2];
#pragma unroll
        for (int a = 0; a < 4; ++a) { acc[a][0] = 0.f; acc[a][1] = 0.f; }
#pragma unroll 4
        for (int j = 0; j < JTOT; ++j) {
            float kv0 = kp0[j], kv1 = kp1[j];
#pragma unroll
            for (int du = 0; du < 4; ++du) {
                float qv = qp[du][j];
                acc[du][0] += qv * kv0;
                acc[du][1] += qv * kv1;
            }
        }
        float* op = att_part + (((size_t)h * Nn + n) * Sn + s) * (WVn * Vn);
#pragma unroll
        for (int du = 0; du < 4; ++du) {
            int u = ut * 4 + du;
            if (u < WVn) {
                op[u * Vn + v0] = acc[du][0];
                if (v0 + 1 < Vn) op[u * Vn + v0 + 1] = acc[du][1];
            }
        }
    }
}

// ---------------------------------------------------------------------------
// K_fin: att = softmax(mask((p0+p1)/512)) * gate + att0
// ---------------------------------------------------------------------------
__global__ __launch_bounds__(128) void k_fin(
    const float* __restrict__ part, const float* __restrict__ graph,
    const float* __restrict__ att0, const float* __restrict__ gate,
    float* __restrict__ att_out) {
    const int s = blockIdx.x, n = blockIdx.y;
    const int u = threadIdx.x;
    if (u >= WVn) return;
    const size_t base = ((size_t)(n * Sn) + s) * (WVn * Vn) + u * Vn;
    const float* p0 = part + base;
    const float* p1 = part + (size_t)Nn * Sn * WVn * Vn + base;
    const int u0 = u % Vn;
    const float* gr = graph + (s * Vn + u0) * Vn;
    float av[Vn];
    float mx = -1e30f;
#pragma unroll
    for (int v = 0; v < Vn; ++v) {
        float a = (p0[v] + p1[v]) * (1.f / 512.f);
        av[v] = (gr[v] > 0.f) ? a : -1e30f;
        mx = fmaxf(mx, av[v]);
    }
    float ssum = 0.f;
#pragma unroll
    for (int v = 0; v < Vn; ++v) {
        float e = (av[v] > -1e29f) ? expf(av[v] - mx) : 0.f;
        av[v] = e;
        ssum += e;
    }
    const float g = gate[(n * Sn + s) * Wn + (u % Wn)];
    const float sc = g / ssum;
    float* op = att_out + base;
    const float* a0 = att0 + (s * WVn + u) * Vn;
#pragma unroll
    for (int v = 0; v < Vn; ++v) op[v] = av[v] * sc + a0[v];
}

// ---------------------------------------------------------------------------
// K3 (unchanged): aggregate + out-proj + BN + leaky + ff + BN + leaky + relu.
// ---------------------------------------------------------------------------
__global__ __launch_bounds__(256) void k_main(
    const float* __restrict__ x, const float* __restrict__ att,
    const float* __restrict__ out_w, const float* __restrict__ out_b,
    const float* __restrict__ og, const float* __restrict__ obeta,
    const float* __restrict__ orm, const float* __restrict__ orv,
    const float* __restrict__ ff_w, const float* __restrict__ ff_b,
    const float* __restrict__ fg, const float* __restrict__ fbeta,
    const float* __restrict__ frm, const float* __restrict__ frv,
    float* __restrict__ out) {
    const int tc = blockIdx.x, n = blockIdx.y;
    const int t0 = tc * 4;
    const int tid = threadIdx.x;
    const int o = tid >> 2, tl = tid & 3;

    __shared__ float xs[6][Cn * Vn + 1];
    __shared__ float ybuf[Cn * 4 * 28];

    for (int i = tid; i < 6 * 1600; i += 256) {
        int r = i / 1600, j = i % 1600;
        int c = j & 63, v = j >> 6;
        int gt = t0 + r - 1;
        xs[r][c * Vn + v] =
            (gt >= 0 && gt < Tn) ? x[((size_t)(n * Cn + c) * Vn + v) * Tn + gt] : 0.f;
    }

    float yo[28];
#pragma unroll
    for (int v = 0; v < 28; ++v) yo[v] = 0.f;
    __syncthreads();

    for (int s = 0; s < Sn; ++s) {
        float acc[Vn];
#pragma unroll
        for (int v = 0; v < Vn; ++v) acc[v] = 0.f;
        const float* atp = att + ((size_t)(n * Sn + s) * WVn) * Vn;
        for (int w = 0; w < Wn; ++w) {
            const float* xrow = &xs[tl + w][o * Vn];
            for (int vv = 0; vv < Vn; ++vv) {
                float xv = xrow[vv];
                const float* arow = atp + (w * Vn + vv) * Vn;  // uniform -> s_load
#pragma unroll
                for (int v = 0; v < Vn; ++v) acc[v] += xv * arow[v];
            }
        }
        float* yrow = &ybuf[(o * 4 + tl) * 28];
#pragma unroll
        for (int v = 0; v < Vn; ++v) yrow[v] = acc[v];
        yrow[25] = 0.f; yrow[26] = 0.f; yrow[27] = 0.f;
        __syncthreads();
        const float4* wrow = (const float4*)(out_w + (size_t)o * (Sn * Cn) + s * Cn);
        for (int c4 = 0; c4 < 16; ++c4) {
            float4 w4 = wrow[c4];
#pragma unroll
            for (int dc = 0; dc < 4; ++dc) {
                int c = c4 * 4 + dc;
                float wv = (dc == 0) ? w4.x : (dc == 1) ? w4.y : (dc == 2) ? w4.z : w4.w;
                const float4* yr4 = (const float4*)&ybuf[(c * 4 + tl) * 28];
#pragma unroll
                for (int v4 = 0; v4 < 7; ++v4) {
                    float4 yv = yr4[v4];
                    yo[v4 * 4 + 0] += wv * yv.x;
                    yo[v4 * 4 + 1] += wv * yv.y;
                    yo[v4 * 4 + 2] += wv * yv.z;
                    yo[v4 * 4 + 3] += wv * yv.w;
                }
            }
        }
        __syncthreads();
    }

    const float sc_o = og[o] * rsqrtf(orv[o] + 1e-5f);
    const float sh_o = obeta[o] - orm[o] * sc_o;
    const float bo = out_b[o];
    const float* xcen = &xs[tl + 1][o * Vn];
    float xres[Vn];
    float* yrow = &ybuf[(o * 4 + tl) * 28];
#pragma unroll
    for (int v = 0; v < Vn; ++v) {
        float xv = xcen[v];
        xres[v] = xv;
        float val = (yo[v] + bo) * sc_o + sh_o;
        float y1 = xv + val;
        yrow[v] = (y1 > 0.f) ? y1 : 0.1f * y1;
    }
    yrow[25] = 0.f; yrow[26] = 0.f; yrow[27] = 0.f;
    __syncthreads();
    float zf[28];
#pragma unroll
    for (int v = 0; v < 28; ++v) zf[v] = 0.f;
    const float4* fw4 = (const float4*)(ff_w + o * Cn);
    for (int c4 = 0; c4 < 16; ++c4) {
        float4 w4 = fw4[c4];
#pragma unroll
        for (int dc = 0; dc < 4; ++dc) {
            int c = c4 * 4 + dc;
            float wv = (dc == 0) ? w4.x : (dc == 1) ? w4.y : (dc == 2) ? w4.z : w4.w;
            const float4* yr4 = (const float4*)&ybuf[(c * 4 + tl) * 28];
#pragma unroll
            for (int v4 = 0; v4 < 7; ++v4) {
                float4 yv = yr4[v4];
                zf[v4 * 4 + 0] += wv * yv.x;
                zf[v4 * 4 + 1] += wv * yv.y;
                zf[v4 * 4 + 2] += wv * yv.z;
                zf[v4 * 4 + 3] += wv * yv.w;
            }
        }
    }
    const float sc_f = fg[o] * rsqrtf(frv[o] + 1e-5f);
    const float sh_f = fbeta[o] - frm[o] * sc_f;
    const float bf = ff_b[o];
#pragma unroll
    for (int v = 0; v < Vn; ++v) {
        float val = (zf[v] + bf) * sc_f + sh_f;
        float y2v = xres[v] + val;
        y2v = (y2v > 0.f) ? y2v : 0.1f * y2v;
        float outv = y2v + xres[v];
        outv = (outv > 0.f) ? outv : 0.f;
        out[((size_t)(n * Cn + o) * Vn + v) * Tn + t0 + tl] = outv;
    }
}

// ---------------------------------------------------------------------------
extern "C" void kernel_launch(void* const* d_in, const int* in_sizes, int n_in,
                              void* d_out, int out_size, void* d_ws, size_t ws_size,
                              hipStream_t stream) {
    const float* x       = (const float*)d_in[0];
    const float* graph   = (const float*)d_in[1];
    const float* graph_a = (const float*)d_in[2];
    const float* in_w    = (const float*)d_in[3];
    const float* in_b    = (const float*)d_in[4];
    const float* inup_w  = (const float*)d_in[5];
    const float* inup_b  = (const float*)d_in[6];
    const float* diff_w  = (const float*)d_in[7];
    const float* diff_b  = (const float*)d_in[8];
    const float* att0    = (const float*)d_in[9];
    const float* out_w   = (const float*)d_in[10];
    const float* out_b   = (const float*)d_in[11];
    const float* og      = (const float*)d_in[12];
    const float* obeta   = (const float*)d_in[13];
    const float* orm     = (const float*)d_in[14];
    const float* orv     = (const float*)d_in[15];
    const float* ff_w    = (const float*)d_in[16];
    const float* ff_b    = (const float*)d_in[17];
    const float* fg      = (const float*)d_in[18];
    const float* fbeta   = (const float*)d_in[19];
    const float* frm     = (const float*)d_in[20];
    const float* frv     = (const float*)d_in[21];
    float* out = (float*)d_out;

    // workspace layout (floats unless noted):
    //   att_final : 0          .. 960,000
    //   red       : 960,000    (+16,384)
    //   gate      : 976,384    (+1,536)
    //   att_part  : 977,920    (+1,920,000)   [2 halves]
    //   pq (bf16) : byte 11,591,680  (+13,107,200 B)
    //   pk (bf16) : byte 24,698,880  (+13,107,200 B)   total ~37.8 MB
    float* ws       = (float*)d_ws;
    float* att_ws   = ws;
    float* red_ws   = ws + 960000;
    float* gate_ws  = ws + 976384;
    float* part_ws  = ws + 977920;
    __hip_bfloat16* pq = (__hip_bfloat16*)((char*)d_ws + 11591680);
    __hip_bfloat16* pk = (__hip_bfloat16*)((char*)d_ws + 24698880);

    k_red<<<dim3(Cn, Nn), 64, 0, stream>>>(x, graph_a, red_ws);
    k_gate<<<dim3(Nn), 64, 0, stream>>>(red_ws, diff_w, diff_b, gate_ws);
    k_proj<<<dim3(Vn, Nn), 256, 0, stream>>>(x, in_w, in_b, inup_w, inup_b, pk, pq);
    k_att2<<<dim3(Sn, Nn, 2), 256, 0, stream>>>(pq, pk, inup_b, part_ws);
    k_fin<<<dim3(Sn, Nn), 128, 0, stream>>>(part_ws, graph, att0, gate_ws, att_ws);
    k_main<<<dim3(Tn / 4, Nn), 256, 0, stream>>>(x, att_ws, out_w, out_b, og, obeta,
                                                 orm, orv, ff_w, ff_b, fg, fbeta,
                                                 frm, frv, out);
}

// Round 3
// 234.568 us; speedup vs baseline: 6.6420x; 3.1997x over previous
//
#include <hip/hip_runtime.h>
#include <hip/hip_bf16.h>
#include <math.h>

#define Nn 64
#define Cn 64
#define Tn 64
#define Vn 25
#define Sn 8
#define ICn 8
#define Wn 3
#define WVn 75

typedef __attribute__((ext_vector_type(8))) short s16x8;   // 8 bf16 (4 VGPR)
typedef __attribute__((ext_vector_type(4))) float f32x4;   // MFMA acc

#define MFMA16(a, b, c) __builtin_amdgcn_mfma_f32_16x16x32_bf16(a, b, c, 0, 0, 0)

static __device__ inline unsigned short f2bf(float f) {
    __hip_bfloat16 h = __float2bfloat16(f);
    return *reinterpret_cast<unsigned short*>(&h);
}
static __device__ inline float bf2f(unsigned short u) {
    union { unsigned int i; float f; } x;
    x.i = ((unsigned int)u) << 16;
    return x.f;
}

// ---------------------------------------------------------------------------
// K1: per (n,c) reductions over x rows (collapsed diff/gate branch).
// ---------------------------------------------------------------------------
__global__ __launch_bounds__(64) void k_red(const float* __restrict__ x,
                                            const float* __restrict__ ga,
                                            float* __restrict__ red) {
    const int c = blockIdx.x, n = blockIdx.y;
    const int lane = threadIdx.x;
    float rs = 0.f, r0 = 0.f, r63 = 0.f, xg = 0.f;
    if (lane < Vn) {
        const float* row = x + ((size_t)(n * Cn + c) * Vn + lane) * Tn;
        float g = 0.f;
        for (int j = 0; j < Vn; ++j) g += ga[lane * Vn + j];
        for (int t = 0; t < Tn; ++t) rs += row[t];
        r0 = row[0];
        r63 = row[Tn - 1];
        xg = rs * g;
    }
    for (int off = 32; off > 0; off >>= 1) {
        rs += __shfl_down(rs, off);
        r0 += __shfl_down(r0, off);
        r63 += __shfl_down(r63, off);
        xg += __shfl_down(xg, off);
    }
    if (lane == 0) {
        float* p = red + (size_t)(n * Cn + c) * 4;
        p[0] = rs; p[1] = r0; p[2] = r63; p[3] = xg;
    }
}

// ---------------------------------------------------------------------------
// K1b: gate[n,s,w]
// ---------------------------------------------------------------------------
__global__ __launch_bounds__(64) void k_gate(const float* __restrict__ red,
                                             const float* __restrict__ diff_w,
                                             const float* __restrict__ diff_b,
                                             float* __restrict__ gate) {
    const int n = blockIdx.x;
    const int s = threadIdx.x;
    if (s >= Sn) return;
    float sumd2 = 0.f, rsum = 0.f, rr0 = 0.f, rr63 = 0.f;
    for (int cc = 0; cc < ICn; ++cc) {
        const int oc = s * ICn + cc;
        float a = 0.f;
        for (int c = 0; c < Cn; ++c)
            a += red[(n * Cn + c) * 4 + 3] * diff_w[oc * Cn + c];
        sumd2 += a + 1600.f * diff_b[oc];
        rsum += red[(n * Cn + oc) * 4 + 0];
        rr0  += red[(n * Cn + oc) * 4 + 1];
        rr63 += red[(n * Cn + oc) * 4 + 2];
    }
    const float inv = 1.f / 12800.f;
    float m0 = (sumd2 - (rsum - rr63)) * inv;
    float m1 = (sumd2 - rsum) * inv;
    float m2 = (sumd2 - (rsum - rr0)) * inv;
    float* gp = gate + (n * Sn + s) * Wn;
    gp[0] = 1.f / (1.f + expf(-m0));
    gp[1] = 1.f / (1.f + expf(-m1));
    gp[2] = 1.f / (1.f + expf(-m2));
}

// ---------------------------------------------------------------------------
// K_conv: out_w / ff_w -> bf16
// ---------------------------------------------------------------------------
__global__ __launch_bounds__(256) void k_conv(const float* __restrict__ ow,
                                              const float* __restrict__ fw,
                                              unsigned short* __restrict__ owb,
                                              unsigned short* __restrict__ fwb) {
    int i = blockIdx.x * 256 + threadIdx.x;
    if (i < 64 * 512) owb[i] = f2bf(ow[i]);
    if (i < 64 * 64)  fwb[i] = f2bf(fw[i]);
}

// ---------------------------------------------------------------------------
// K_proj: q/k conv1x1 projections -> bf16 (coalesced along t)
// ---------------------------------------------------------------------------
__global__ __launch_bounds__(256) void k_proj(
    const float* __restrict__ x,
    const float* __restrict__ in_w, const float* __restrict__ in_b,
    const float* __restrict__ inup_w, const float* __restrict__ inup_b,
    __hip_bfloat16* __restrict__ pk, __hip_bfloat16* __restrict__ pq) {
    const int v = blockIdx.x, n = blockIdx.y;
    const int tid = threadIdx.x;
    __shared__ float xs[64 * 65];
    __shared__ float wk[64 * 65];
    __shared__ float wq[64 * 65];

    for (int i = tid; i < 4096; i += 256) {
        int o = i >> 6, c = i & 63;
        wk[o * 65 + c] = in_w[i];
        wq[o * 65 + c] = inup_w[i];
    }
    for (int i = tid; i < 4096; i += 256) {
        int c = i >> 6, t = i & 63;
        xs[c * 65 + t] = x[((size_t)(n * Cn + c) * Vn + v) * Tn + t];
    }
    __syncthreads();

    const int o = tid >> 2, tq = tid & 3;
    float ak[16], aq[16];
#pragma unroll
    for (int t = 0; t < 16; ++t) { ak[t] = 0.f; aq[t] = 0.f; }
    for (int c = 0; c < 64; ++c) {
        float wkc = wk[o * 65 + c], wqc = wq[o * 65 + c];
        const float* xr = &xs[c * 65 + tq * 16];
#pragma unroll
        for (int t = 0; t < 16; ++t) {
            float xv = xr[t];
            ak[t] += wkc * xv;
            aq[t] += wqc * xv;
        }
    }
    const float bk = in_b[o], bq = inup_b[o];
    const size_t base = ((size_t)(n * Cn + o) * Vn + v) * Tn + tq * 16;
#pragma unroll
    for (int t = 0; t < 16; ++t) {
        pk[base + t] = __float2bfloat16(ak[t] + bk);
        pq[base + t] = __float2bfloat16(aq[t] + bq);
    }
}

// ---------------------------------------------------------------------------
// K_att2: partial attention logits (shifted-window dot via flat LDS slabs)
// ---------------------------------------------------------------------------
#define ROWL 273
#define JTOT 272
__global__ __launch_bounds__(256) void k_att2(
    const __hip_bfloat16* __restrict__ pq, const __hip_bfloat16* __restrict__ pk,
    const float* __restrict__ inup_b, float* __restrict__ att_part) {
    const int s = blockIdx.x, n = blockIdx.y, h = blockIdx.z;
    const int tid = threadIdx.x;
    __shared__ float slab[26 * ROWL + 25 * ROWL];
    float* ksl = slab;
    float* qsl = slab + 26 * ROWL;

    for (int i = tid; i < 51 * ROWL; i += 256) slab[i] = 0.f;
    __syncthreads();

    for (int i = tid; i < 6400; i += 256) {
        int tt = i & 31, v = (i >> 5) % 25, cc = i / 800;
        float val = __bfloat162float(
            pk[((size_t)(n * Cn + s * ICn + cc) * Vn + v) * Tn + h * 32 + tt]);
        ksl[v * ROWL + cc * 34 + 1 + tt] = val;
    }
    for (int i = tid; i < 6800; i += 256) {
        int slot = i % 34, uu = (i / 34) % 25, cc = i / 850;
        int tg = h * 32 - 1 + slot;
        int ch = s * ICn + cc;
        float val = (tg >= 0 && tg < Tn)
            ? __bfloat162float(pq[((size_t)(n * Cn + ch) * Vn + uu) * Tn + tg])
            : inup_b[ch];
        qsl[uu * ROWL + cc * 34 + slot] = val;
    }
    __syncthreads();

    if (tid < 247) {
        const int ut = tid / 13, vt = tid % 13;
        const int v0 = vt * 2;
        const float* kp0 = &ksl[v0 * ROWL];
        const float* kp1 = &ksl[(v0 + 1) * ROWL];
        const float* qp[4];
#pragma unroll
        for (int du = 0; du < 4; ++du) {
            int u = ut * 4 + du;
            int w = (u < WVn) ? u / Vn : 1;
            int uu = (u < WVn) ? u % Vn : 0;
            qp[du] = &qsl[uu * ROWL + (w - 1)];
        }
        float acc[4][2];
#pragma unroll
        for (int a = 0; a < 4; ++a) { acc[a][0] = 0.f; acc[a][1] = 0.f; }
#pragma unroll 4
        for (int j = 0; j < JTOT; ++j) {
            float kv0 = kp0[j], kv1 = kp1[j];
#pragma unroll
            for (int du = 0; du < 4; ++du) {
                float qv = qp[du][j];
                acc[du][0] += qv * kv0;
                acc[du][1] += qv * kv1;
            }
        }
        float* op = att_part + (((size_t)h * Nn + n) * Sn + s) * (WVn * Vn);
#pragma unroll
        for (int du = 0; du < 4; ++du) {
            int u = ut * 4 + du;
            if (u < WVn) {
                op[u * Vn + v0] = acc[du][0];
                if (v0 + 1 < Vn) op[u * Vn + v0 + 1] = acc[du][1];
            }
        }
    }
}

// ---------------------------------------------------------------------------
// K_fin2: softmax/mask/gate/att0, then emit attB bf16 in MFMA-B layout:
//   attB[n][s][v(32)][k(96)], k = w*32 + v' (w-padded; zero at v'>=25, v>=25)
// ---------------------------------------------------------------------------
__global__ __launch_bounds__(128) void k_fin2(
    const float* __restrict__ part, const float* __restrict__ graph,
    const float* __restrict__ att0, const float* __restrict__ gate,
    unsigned short* __restrict__ attB) {
    const int s = blockIdx.x, n = blockIdx.y;
    const int tid = threadIdx.x;
    __shared__ float al[WVn * Vn];

    if (tid < WVn) {
        const int u = tid;
        const size_t base = ((size_t)(n * Sn) + s) * (WVn * Vn) + u * Vn;
        const float* p0 = part + base;
        const float* p1 = part + (size_t)Nn * Sn * WVn * Vn + base;
        const int u0 = u % Vn;
        const float* gr = graph + (s * Vn + u0) * Vn;
        float av[Vn];
        float mx = -1e30f;
#pragma unroll
        for (int v = 0; v < Vn; ++v) {
            float a = (p0[v] + p1[v]) * (1.f / 512.f);
            av[v] = (gr[v] > 0.f) ? a : -1e30f;
            mx = fmaxf(mx, av[v]);
        }
        float ssum = 0.f;
#pragma unroll
        for (int v = 0; v < Vn; ++v) {
            float e = (av[v] > -1e29f) ? expf(av[v] - mx) : 0.f;
            av[v] = e;
            ssum += e;
        }
        const float g = gate[(n * Sn + s) * Wn + (u % Wn)];
        const float sc = g / ssum;
        const float* a0 = att0 + (s * WVn + u) * Vn;
#pragma unroll
        for (int v = 0; v < Vn; ++v) al[u * Vn + v] = av[v] * sc + a0[v];
    }
    __syncthreads();
    unsigned short* ab = attB + ((size_t)(n * Sn + s)) * 32 * 96;
    for (int i = tid; i < 32 * 96; i += 128) {
        int v = i / 96, k = i % 96;
        int w = k >> 5, vp = k & 31;
        float val = (v < Vn && vp < Vn) ? al[(w * Vn + vp) * Vn + v] : 0.f;
        ab[i] = f2bf(val);
    }
}

// ---------------------------------------------------------------------------
// K_main2 (MFMA): per (t-chunk 8, n) block, 4 waves.
//   stage1 (per s): y2_s[c,t,v] via mfma_16x16x32: M=(2c x 8t) tiles,
//     K=96 (3 w-blocks of 32 v'), N=32 (v). C -> ybuf bf16 [tv=v*8+t][c swz].
//   stage2: accO[o, (v,t)] += out_w[o, s*64+c] * y2_s  (acc across s)
//   epi1:  y1 = leaky(x + BN(accO)) -> ybuf [tv][o swz]
//   ff:    accF = ff_w * y1;  epi2: relu(leaky(x+BNf)+x) -> out (coalesced t)
// ybuf stride 72 + (c ^ ((v&7)<<3)) swizzle: bank-floor b128 reads/b16 writes.
// ---------------------------------------------------------------------------
__global__ __launch_bounds__(256, 2) void k_main2(
    const float* __restrict__ x, const unsigned short* __restrict__ attB,
    const unsigned short* __restrict__ out_wbf, const float* __restrict__ out_b,
    const float* __restrict__ og, const float* __restrict__ obeta,
    const float* __restrict__ orm, const float* __restrict__ orv,
    const unsigned short* __restrict__ ff_wbf, const float* __restrict__ ff_b,
    const float* __restrict__ fg, const float* __restrict__ fbeta,
    const float* __restrict__ frm, const float* __restrict__ frv,
    float* __restrict__ out) {
    const int tc = blockIdx.x, n = blockIdx.y;
    const int t0 = tc * 8;
    const int tid = threadIdx.x;
    const int lane = tid & 63, wv = tid >> 6;
    const int r16 = lane & 15, g4 = lane >> 4;

    __shared__ unsigned short xs[64 * 10 * 32];  // [c][tau 0..9][v pad32] bf16
    __shared__ unsigned short ybuf[208 * 72];    // [tv=v*8+t][c^swz] bf16
    __shared__ float bnp[384];                   // sc_o|sh_o|bo|sc_f|sh_f|bf

    for (int i = tid; i < 8 * 72; i += 256) ybuf[200 * 72 + i] = 0;
    if (tid < 64) {
        int o = tid;
        float so = og[o] * rsqrtf(orv[o] + 1e-5f);
        bnp[o] = so; bnp[64 + o] = obeta[o] - orm[o] * so; bnp[128 + o] = out_b[o];
        float sf = fg[o] * rsqrtf(frv[o] + 1e-5f);
        bnp[192 + o] = sf; bnp[256 + o] = fbeta[o] - frm[o] * sf; bnp[320 + o] = ff_b[o];
    }
    // stage x window: tau row 0 <-> global t = t0-1+tau; zero pad t/v OOB
    for (int p = tid; p < 64 * 32; p += 256) {
        int c = p >> 5, v = p & 31;
        const float* xr = x + ((size_t)(n * Cn + c) * Vn + (v < Vn ? v : 0)) * Tn;
#pragma unroll
        for (int tau = 0; tau < 10; ++tau) {
            int tg = t0 - 1 + tau;
            float val = (v < Vn && tg >= 0 && tg < Tn) ? xr[tg] : 0.f;
            xs[(c * 10 + tau) * 32 + v] = f2bf(val);
        }
    }
    __syncthreads();

    f32x4 accO[13];
#pragma unroll
    for (int i = 0; i < 13; ++i) accO[i] = (f32x4){0.f, 0.f, 0.f, 0.f};

    for (int s = 0; s < Sn; ++s) {
        // ---- stage1: wave wv owns c in [wv*16, wv*16+16)
        const unsigned short* aB = attB + ((size_t)(n * Sn + s)) * 32 * 96;
        s16x8 bfr[3][2];
#pragma unroll
        for (int k = 0; k < 3; ++k)
#pragma unroll
            for (int nt = 0; nt < 2; ++nt)
                bfr[k][nt] = *(const s16x8*)(aB + (nt * 16 + r16) * 96 + k * 32 + g4 * 8);
        const int cl = r16 >> 3, tl = r16 & 7;
#pragma unroll
        for (int m = 0; m < 8; ++m) {
            const int c0 = wv * 16 + m * 2;
            f32x4 a0 = (f32x4){0.f, 0.f, 0.f, 0.f};
            f32x4 a1 = (f32x4){0.f, 0.f, 0.f, 0.f};
#pragma unroll
            for (int k = 0; k < 3; ++k) {
                const s16x8 af = *(const s16x8*)&xs[((c0 + cl) * 10 + tl + k) * 32 + g4 * 8];
                a0 = MFMA16(af, bfr[k][0], a0);
                a1 = MFMA16(af, bfr[k][1], a1);
            }
#pragma unroll
            for (int r = 0; r < 4; ++r) {
                int row = g4 * 4 + r;
                int cc = c0 + (row >> 3), tt = row & 7;
                int v0 = r16;
                ybuf[(v0 * 8 + tt) * 72 + (cc ^ ((v0 & 7) << 3))] = f2bf(a0[r]);
                int v1 = 16 + r16;
                if (v1 < Vn)
                    ybuf[(v1 * 8 + tt) * 72 + (cc ^ ((v1 & 7) << 3))] = f2bf(a1[r]);
            }
        }
        __syncthreads();
        // ---- stage2: accO += out_w[o, s*64+c] * y2_s
        const unsigned short* wO = out_wbf + (size_t)(wv * 16) * 512 + s * 64;
        const s16x8 wa0 = *(const s16x8*)(wO + (size_t)r16 * 512 + g4 * 8);
        const s16x8 wa1 = *(const s16x8*)(wO + (size_t)r16 * 512 + 32 + g4 * 8);
#pragma unroll
        for (int nt = 0; nt < 13; ++nt) {
            int v = nt * 2 + (r16 >> 3), tt = r16 & 7;
            int tv = v * 8 + tt;
            const s16x8 b0 = *(const s16x8*)&ybuf[tv * 72 + ((g4 * 8) ^ ((v & 7) << 3))];
            const s16x8 b1 = *(const s16x8*)&ybuf[tv * 72 + ((32 + g4 * 8) ^ ((v & 7) << 3))];
            accO[nt] = MFMA16(wa0, b0, accO[nt]);
            accO[nt] = MFMA16(wa1, b1, accO[nt]);
        }
        __syncthreads();
    }

    // ---- epilogue1: y1 = leaky(x + BN(accO)) -> ybuf [tv][o]
#pragma unroll
    for (int nt = 0; nt < 13; ++nt) {
        int v = nt * 2 + (r16 >> 3), tt = r16 & 7;
        if (v < Vn) {
#pragma unroll
            for (int r = 0; r < 4; ++r) {
                int o = wv * 16 + g4 * 4 + r;
                float xv = bf2f(xs[(o * 10 + tt + 1) * 32 + v]);
                float val = (accO[nt][r] + bnp[128 + o]) * bnp[o] + bnp[64 + o];
                float y1 = xv + val;
                y1 = (y1 > 0.f) ? y1 : 0.1f * y1;
                ybuf[(v * 8 + tt) * 72 + (o ^ ((v & 7) << 3))] = f2bf(y1);
            }
        }
    }
    __syncthreads();
    // ---- ff
    f32x4 accF[13];
#pragma unroll
    for (int i = 0; i < 13; ++i) accF[i] = (f32x4){0.f, 0.f, 0.f, 0.f};
    const unsigned short* wF = ff_wbf + (size_t)(wv * 16) * 64;
    const s16x8 fa0 = *(const s16x8*)(wF + (size_t)r16 * 64 + g4 * 8);
    const s16x8 fa1 = *(const s16x8*)(wF + (size_t)r16 * 64 + 32 + g4 * 8);
#pragma unroll
    for (int nt = 0; nt < 13; ++nt) {
        int v = nt * 2 + (r16 >> 3), tt = r16 & 7;
        int tv = v * 8 + tt;
        const s16x8 b0 = *(const s16x8*)&ybuf[tv * 72 + ((g4 * 8) ^ ((v & 7) << 3))];
        const s16x8 b1 = *(const s16x8*)&ybuf[tv * 72 + ((32 + g4 * 8) ^ ((v & 7) << 3))];
        accF[nt] = MFMA16(fa0, b0, accF[nt]);
        accF[nt] = MFMA16(fa1, b1, accF[nt]);
    }
    // ---- epilogue2 + store (t-coalesced)
#pragma unroll
    for (int nt = 0; nt < 13; ++nt) {
        int v = nt * 2 + (r16 >> 3), tt = r16 & 7;
        if (v < Vn) {
#pragma unroll
            for (int r = 0; r < 4; ++r) {
                int o = wv * 16 + g4 * 4 + r;
                float xv = bf2f(xs[(o * 10 + tt + 1) * 32 + v]);
                float val = (accF[nt][r] + bnp[320 + o]) * bnp[192 + o] + bnp[256 + o];
                float y2v = xv + val;
                y2v = (y2v > 0.f) ? y2v : 0.1f * y2v;
                float outv = y2v + xv;
                outv = (outv > 0.f) ? outv : 0.f;
                out[((size_t)(n * Cn + o) * Vn + v) * Tn + t0 + tt] = outv;
            }
        }
    }
}

// ---------------------------------------------------------------------------
extern "C" void kernel_launch(void* const* d_in, const int* in_sizes, int n_in,
                              void* d_out, int out_size, void* d_ws, size_t ws_size,
                              hipStream_t stream) {
    const float* x       = (const float*)d_in[0];
    const float* graph   = (const float*)d_in[1];
    const float* graph_a = (const float*)d_in[2];
    const float* in_w    = (const float*)d_in[3];
    const float* in_b    = (const float*)d_in[4];
    const float* inup_w  = (const float*)d_in[5];
    const float* inup_b  = (const float*)d_in[6];
    const float* diff_w  = (const float*)d_in[7];
    const float* diff_b  = (const float*)d_in[8];
    const float* att0    = (const float*)d_in[9];
    const float* out_w   = (const float*)d_in[10];
    const float* out_b   = (const float*)d_in[11];
    const float* og      = (const float*)d_in[12];
    const float* obeta   = (const float*)d_in[13];
    const float* orm     = (const float*)d_in[14];
    const float* orv     = (const float*)d_in[15];
    const float* ff_w    = (const float*)d_in[16];
    const float* ff_b    = (const float*)d_in[17];
    const float* fg      = (const float*)d_in[18];
    const float* fbeta   = (const float*)d_in[19];
    const float* frm     = (const float*)d_in[20];
    const float* frv     = (const float*)d_in[21];
    float* out = (float*)d_out;

    // ws layout (bytes):
    //   red      @ 0         (65,536)
    //   gate     @ 65,536    (6,144)
    //   part     @ 71,680    (7,680,000)
    //   attB     @ 7,751,680 (3,145,728)  bf16 [n][s][32][96]
    //   out_wbf  @ 10,897,408 (65,536)
    //   ff_wbf   @ 10,962,944 (8,192)
    //   pq       @ 10,971,136 (13,107,200)
    //   pk       @ 24,078,336 (13,107,200)   total ~37.2 MB
    char* wsb = (char*)d_ws;
    float* red_ws  = (float*)(wsb);
    float* gate_ws = (float*)(wsb + 65536);
    float* part_ws = (float*)(wsb + 71680);
    unsigned short* attB  = (unsigned short*)(wsb + 7751680);
    unsigned short* owb   = (unsigned short*)(wsb + 10897408);
    unsigned short* fwb   = (unsigned short*)(wsb + 10962944);
    __hip_bfloat16* pq = (__hip_bfloat16*)(wsb + 10971136);
    __hip_bfloat16* pk = (__hip_bfloat16*)(wsb + 24078336);

    k_red<<<dim3(Cn, Nn), 64, 0, stream>>>(x, graph_a, red_ws);
    k_gate<<<dim3(Nn), 64, 0, stream>>>(red_ws, diff_w, diff_b, gate_ws);
    k_conv<<<dim3(128), 256, 0, stream>>>(out_w, ff_w, owb, fwb);
    k_proj<<<dim3(Vn, Nn), 256, 0, stream>>>(x, in_w, in_b, inup_w, inup_b, pk, pq);
    k_att2<<<dim3(Sn, Nn, 2), 256, 0, stream>>>(pq, pk, inup_b, part_ws);
    k_fin2<<<dim3(Sn, Nn), 128, 0, stream>>>(part_ws, graph, att0, gate_ws, attB);
    k_main2<<<dim3(Tn / 8, Nn), 256, 0, stream>>>(x, attB, owb, out_b, og, obeta,
                                                  orm, orv, fwb, ff_b, fg, fbeta,
                                                  frm, frv, out);
}

// Round 4
// 200.924 us; speedup vs baseline: 7.7542x; 1.1674x over previous
//
#include <hip/hip_runtime.h>
#include <hip/hip_bf16.h>
#include <math.h>

#define Nn 64
#define Cn 64
#define Tn 64
#define Vn 25
#define Sn 8
#define ICn 8
#define Wn 3
#define WVn 75

typedef __attribute__((ext_vector_type(8))) short s16x8;   // 8 bf16 (4 VGPR)
typedef __attribute__((ext_vector_type(4))) float f32x4;   // MFMA acc

#define MFMA16(a, b, c) __builtin_amdgcn_mfma_f32_16x16x32_bf16(a, b, c, 0, 0, 0)

static __device__ inline unsigned short f2bf(float f) {
    __hip_bfloat16 h = __float2bfloat16(f);
    return *reinterpret_cast<unsigned short*>(&h);
}
static __device__ inline float bf2f(unsigned short u) {
    union { unsigned int i; float f; } x;
    x.i = ((unsigned int)u) << 16;
    return x.f;
}

// ---------------------------------------------------------------------------
// K1: per (n,c) reductions over x rows (collapsed diff/gate branch).
// ---------------------------------------------------------------------------
__global__ __launch_bounds__(64) void k_red(const float* __restrict__ x,
                                            const float* __restrict__ ga,
                                            float* __restrict__ red) {
    const int c = blockIdx.x, n = blockIdx.y;
    const int lane = threadIdx.x;
    float rs = 0.f, r0 = 0.f, r63 = 0.f, xg = 0.f;
    if (lane < Vn) {
        const float* row = x + ((size_t)(n * Cn + c) * Vn + lane) * Tn;
        float g = 0.f;
        for (int j = 0; j < Vn; ++j) g += ga[lane * Vn + j];
        for (int t = 0; t < Tn; ++t) rs += row[t];
        r0 = row[0];
        r63 = row[Tn - 1];
        xg = rs * g;
    }
    for (int off = 32; off > 0; off >>= 1) {
        rs += __shfl_down(rs, off);
        r0 += __shfl_down(r0, off);
        r63 += __shfl_down(r63, off);
        xg += __shfl_down(xg, off);
    }
    if (lane == 0) {
        float* p = red + (size_t)(n * Cn + c) * 4;
        p[0] = rs; p[1] = r0; p[2] = r63; p[3] = xg;
    }
}

// ---------------------------------------------------------------------------
// K1b: gate[n,s,w]
// ---------------------------------------------------------------------------
__global__ __launch_bounds__(64) void k_gate(const float* __restrict__ red,
                                             const float* __restrict__ diff_w,
                                             const float* __restrict__ diff_b,
                                             float* __restrict__ gate) {
    const int n = blockIdx.x;
    const int s = threadIdx.x;
    if (s >= Sn) return;
    float sumd2 = 0.f, rsum = 0.f, rr0 = 0.f, rr63 = 0.f;
    for (int cc = 0; cc < ICn; ++cc) {
        const int oc = s * ICn + cc;
        float a = 0.f;
        for (int c = 0; c < Cn; ++c)
            a += red[(n * Cn + c) * 4 + 3] * diff_w[oc * Cn + c];
        sumd2 += a + 1600.f * diff_b[oc];
        rsum += red[(n * Cn + oc) * 4 + 0];
        rr0  += red[(n * Cn + oc) * 4 + 1];
        rr63 += red[(n * Cn + oc) * 4 + 2];
    }
    const float inv = 1.f / 12800.f;
    float m0 = (sumd2 - (rsum - rr63)) * inv;
    float m1 = (sumd2 - rsum) * inv;
    float m2 = (sumd2 - (rsum - rr0)) * inv;
    float* gp = gate + (n * Sn + s) * Wn;
    gp[0] = 1.f / (1.f + expf(-m0));
    gp[1] = 1.f / (1.f + expf(-m1));
    gp[2] = 1.f / (1.f + expf(-m2));
}

// ---------------------------------------------------------------------------
// K_conv: out_w / ff_w -> bf16
// ---------------------------------------------------------------------------
__global__ __launch_bounds__(256) void k_conv(const float* __restrict__ ow,
                                              const float* __restrict__ fw,
                                              unsigned short* __restrict__ owb,
                                              unsigned short* __restrict__ fwb) {
    int i = blockIdx.x * 256 + threadIdx.x;
    if (i < 64 * 512) owb[i] = f2bf(ow[i]);
    if (i < 64 * 64)  fwb[i] = f2bf(fw[i]);
}

// ---------------------------------------------------------------------------
// K_proj: q/k conv1x1 projections -> bf16 (coalesced along t)
// ---------------------------------------------------------------------------
__global__ __launch_bounds__(256) void k_proj(
    const float* __restrict__ x,
    const float* __restrict__ in_w, const float* __restrict__ in_b,
    const float* __restrict__ inup_w, const float* __restrict__ inup_b,
    __hip_bfloat16* __restrict__ pk, __hip_bfloat16* __restrict__ pq) {
    const int v = blockIdx.x, n = blockIdx.y;
    const int tid = threadIdx.x;
    __shared__ float xs[64 * 65];
    __shared__ float wk[64 * 65];
    __shared__ float wq[64 * 65];

    for (int i = tid; i < 4096; i += 256) {
        int o = i >> 6, c = i & 63;
        wk[o * 65 + c] = in_w[i];
        wq[o * 65 + c] = inup_w[i];
    }
    for (int i = tid; i < 4096; i += 256) {
        int c = i >> 6, t = i & 63;
        xs[c * 65 + t] = x[((size_t)(n * Cn + c) * Vn + v) * Tn + t];
    }
    __syncthreads();

    const int o = tid >> 2, tq = tid & 3;
    float ak[16], aq[16];
#pragma unroll
    for (int t = 0; t < 16; ++t) { ak[t] = 0.f; aq[t] = 0.f; }
    for (int c = 0; c < 64; ++c) {
        float wkc = wk[o * 65 + c], wqc = wq[o * 65 + c];
        const float* xr = &xs[c * 65 + tq * 16];
#pragma unroll
        for (int t = 0; t < 16; ++t) {
            float xv = xr[t];
            ak[t] += wkc * xv;
            aq[t] += wqc * xv;
        }
    }
    const float bk = in_b[o], bq = inup_b[o];
    const size_t base = ((size_t)(n * Cn + o) * Vn + v) * Tn + tq * 16;
#pragma unroll
    for (int t = 0; t < 16; ++t) {
        pk[base + t] = __float2bfloat16(ak[t] + bk);
        pq[base + t] = __float2bfloat16(aq[t] + bq);
    }
}

// ---------------------------------------------------------------------------
// K_att3 (MFMA): fused attention logits + softmax + gate + att0 -> attB.
// Per (s,n) block, 4 waves. GEMM: M=u(80, 5 tiles), N=v(32, 2 tiles),
// K=(t,cc) 512 ordered k = t*8+cc so the window shift (t+w-1) is a
// t-major slot offset -> A-frag reads stay 16B-aligned.
//   QS[uu(25)][slot st 0..65][cc(8)]: value q(cc,uu,st-1); st 0/65 = bias.
//   KS[v(32)][(t ^ (v&7))*8 + cc]: XOR-swizzled for bank spread; v>=25 zero.
// A-frag (tile mt, kstep kb): u=mt*16+r16, w=u/25, uu=u%25:
//   QS[uu*536 + (kb*4+g4+w)*8 .. +8]
// B-frag: KS[v*512 + (((kb*4+g4)^(v&7))*8) .. +8], v=nt*16+r16.
// C: attL[u][v] f32 -> softmax rows (75 threads) -> attB[v32][k96] bf16.
// ---------------------------------------------------------------------------
__global__ __launch_bounds__(256) void k_att3(
    const __hip_bfloat16* __restrict__ pq, const __hip_bfloat16* __restrict__ pk,
    const float* __restrict__ inup_b, const float* __restrict__ graph,
    const float* __restrict__ att0, const float* __restrict__ gate,
    unsigned short* __restrict__ attB) {
    const int s = blockIdx.x, n = blockIdx.y;
    const int tid = threadIdx.x;
    const int lane = tid & 63, wv = tid >> 6;
    const int r16 = lane & 15, g4 = lane >> 4;

    __shared__ unsigned short QS[25 * 536];   // 26.8 KB
    __shared__ unsigned short KS[32 * 512];   // 32 KB
    __shared__ float attL[80 * 33];           // 10.56 KB

    // ---- stage K: (v, cc, tchunk) grid; v>=25 rows zero
    for (int i = tid; i < 2048; i += 256) {
        const int tch = i & 7, cc = (i >> 3) & 7, v = i >> 6;
        if (v < Vn) {
            const s16x8 d = *(const s16x8*)(pk +
                (((size_t)(n * Cn + s * ICn + cc) * Vn + v) * Tn + tch * 8));
#pragma unroll
            for (int j = 0; j < 8; ++j)
                KS[v * 512 + ((((tch * 8 + j)) ^ (v & 7)) << 3) + cc] = ((const unsigned short*)&d)[j];
        } else {
#pragma unroll
            for (int j = 0; j < 8; ++j)
                KS[v * 512 + ((((tch * 8 + j)) ^ (v & 7)) << 3) + cc] = 0;
        }
    }
    // ---- stage Q: (uu, cc, tchunk); slot = t+1
    for (int i = tid; i < 1600; i += 256) {
        const int tch = i & 7, cc = (i >> 3) & 7, uu = i >> 6;
        const s16x8 d = *(const s16x8*)(pq +
            (((size_t)(n * Cn + s * ICn + cc) * Vn + uu) * Tn + tch * 8));
#pragma unroll
        for (int j = 0; j < 8; ++j)
            QS[uu * 536 + (tch * 8 + j + 1) * 8 + cc] = ((const unsigned short*)&d)[j];
    }
    if (tid < 200) {  // bias edge slots (zero-pad rows project to bias)
        const int uu = tid >> 3, cc = tid & 7;
        const unsigned short b = f2bf(inup_b[s * ICn + cc]);
        QS[uu * 536 + 0 * 8 + cc] = b;
        QS[uu * 536 + 65 * 8 + cc] = b;
    }
    __syncthreads();

    // ---- MFMA: 10 tiles round-robin over 4 waves
    for (int tile = wv; tile < 10; tile += 4) {
        const int mt = tile >> 1, nt = tile & 1;
        const int u = mt * 16 + r16;
        const int w = u / 25, uu = u % 25;
        const int v = nt * 16 + r16;
        const unsigned short* qbase = &QS[uu * 536 + (g4 + w) * 8];
        const unsigned short* kbase = &KS[v * 512];
        f32x4 acc = (f32x4){0.f, 0.f, 0.f, 0.f};
#pragma unroll
        for (int kb = 0; kb < 16; ++kb) {
            const s16x8 af = *(const s16x8*)(qbase + kb * 32);
            const s16x8 bf = *(const s16x8*)(kbase + (((kb * 4 + g4) ^ (v & 7)) << 3));
            acc = MFMA16(af, bf, acc);
        }
#pragma unroll
        for (int r = 0; r < 4; ++r)
            attL[(mt * 16 + g4 * 4 + r) * 33 + v] = acc[r];
    }
    __syncthreads();

    // ---- masked softmax * gate + att0 (75 rows)
    if (tid < WVn) {
        const int u = tid, u0 = u % Vn;
        const float* gr = graph + (s * Vn + u0) * Vn;
        float av[Vn];
        float mx = -1e30f;
#pragma unroll
        for (int v = 0; v < Vn; ++v) {
            float a = attL[u * 33 + v] * (1.f / 512.f);
            av[v] = (gr[v] > 0.f) ? a : -1e30f;
            mx = fmaxf(mx, av[v]);
        }
        float ssum = 0.f;
#pragma unroll
        for (int v = 0; v < Vn; ++v) {
            float e = (av[v] > -1e29f) ? expf(av[v] - mx) : 0.f;
            av[v] = e;
            ssum += e;
        }
        const float g = gate[(n * Sn + s) * Wn + (u % Wn)];
        const float sc = g / ssum;
        const float* a0 = att0 + (s * WVn + u) * Vn;
#pragma unroll
        for (int v = 0; v < Vn; ++v) attL[u * 33 + v] = av[v] * sc + a0[v];
    }
    __syncthreads();

    // ---- emit attB[v(32)][k = w*32+vp (96)] bf16, coalesced
    unsigned short* ab = attB + ((size_t)(n * Sn + s)) * 32 * 96;
    for (int i = tid; i < 32 * 96; i += 256) {
        const int v = i / 96, kk = i % 96;
        const int w2 = kk >> 5, vp = kk & 31;
        float val = (v < Vn && vp < Vn) ? attL[(w2 * Vn + vp) * 33 + v] : 0.f;
        ab[i] = f2bf(val);
    }
}

// ---------------------------------------------------------------------------
// K_main3 (MFMA, t-chunk 4): per (tc, n) block, 4 waves, 41 KB LDS -> 3/CU.
//   stage1 (per s): y2_s via mfma: M=(4c x 4t) tiles, K=96, N=32(v).
//   stage2: accO[o,(v,t)] += out_w * y2_s; epi1 -> ybuf; ff; epi2 -> out.
// ---------------------------------------------------------------------------
__global__ __launch_bounds__(256, 3) void k_main3(
    const float* __restrict__ x, const unsigned short* __restrict__ attB,
    const unsigned short* __restrict__ out_wbf, const float* __restrict__ out_b,
    const float* __restrict__ og, const float* __restrict__ obeta,
    const float* __restrict__ orm, const float* __restrict__ orv,
    const unsigned short* __restrict__ ff_wbf, const float* __restrict__ ff_b,
    const float* __restrict__ fg, const float* __restrict__ fbeta,
    const float* __restrict__ frm, const float* __restrict__ frv,
    float* __restrict__ out) {
    const int tc = blockIdx.x, n = blockIdx.y;
    const int t0 = tc * 4;
    const int tid = threadIdx.x;
    const int lane = tid & 63, wv = tid >> 6;
    const int r16 = lane & 15, g4 = lane >> 4;

    __shared__ unsigned short xs[64 * 6 * 32];   // [c][tau 0..5][v pad32] 24.6KB
    __shared__ unsigned short ybuf[112 * 72];    // [tv=v*4+t][c^swz] 16.1KB
    __shared__ float bnp[384];

    for (int i = tid; i < 12 * 72; i += 256) ybuf[100 * 72 + i] = 0;
    if (tid < 64) {
        int o = tid;
        float so = og[o] * rsqrtf(orv[o] + 1e-5f);
        bnp[o] = so; bnp[64 + o] = obeta[o] - orm[o] * so; bnp[128 + o] = out_b[o];
        float sf = fg[o] * rsqrtf(frv[o] + 1e-5f);
        bnp[192 + o] = sf; bnp[256 + o] = fbeta[o] - frm[o] * sf; bnp[320 + o] = ff_b[o];
    }
    for (int p = tid; p < 64 * 32; p += 256) {
        int c = p >> 5, v = p & 31;
        const float* xr = x + ((size_t)(n * Cn + c) * Vn + (v < Vn ? v : 0)) * Tn;
#pragma unroll
        for (int tau = 0; tau < 6; ++tau) {
            int tg = t0 - 1 + tau;
            float val = (v < Vn && tg >= 0 && tg < Tn) ? xr[tg] : 0.f;
            xs[(c * 6 + tau) * 32 + v] = f2bf(val);
        }
    }
    __syncthreads();

    f32x4 accO[7];
#pragma unroll
    for (int i = 0; i < 7; ++i) accO[i] = (f32x4){0.f, 0.f, 0.f, 0.f};

    for (int s = 0; s < Sn; ++s) {
        // ---- stage1: wave wv owns c in [wv*16, wv*16+16)
        const unsigned short* aB = attB + ((size_t)(n * Sn + s)) * 32 * 96;
        s16x8 bfr[3][2];
#pragma unroll
        for (int k = 0; k < 3; ++k)
#pragma unroll
            for (int nt = 0; nt < 2; ++nt)
                bfr[k][nt] = *(const s16x8*)(aB + (nt * 16 + r16) * 96 + k * 32 + g4 * 8);
        const int cl = r16 >> 2, tl = r16 & 3;
#pragma unroll
        for (int m = 0; m < 4; ++m) {
            const int c0 = wv * 16 + m * 4;
            f32x4 a0 = (f32x4){0.f, 0.f, 0.f, 0.f};
            f32x4 a1 = (f32x4){0.f, 0.f, 0.f, 0.f};
#pragma unroll
            for (int k = 0; k < 3; ++k) {
                const s16x8 af = *(const s16x8*)&xs[((c0 + cl) * 6 + tl + k) * 32 + g4 * 8];
                a0 = MFMA16(af, bfr[k][0], a0);
                a1 = MFMA16(af, bfr[k][1], a1);
            }
#pragma unroll
            for (int r = 0; r < 4; ++r) {
                int row = g4 * 4 + r;
                int cc = c0 + (row >> 2), tt = row & 3;
                int v0 = r16;
                ybuf[(v0 * 4 + tt) * 72 + (cc ^ ((v0 & 7) << 3))] = f2bf(a0[r]);
                int v1 = 16 + r16;
                if (v1 < Vn)
                    ybuf[(v1 * 4 + tt) * 72 + (cc ^ ((v1 & 7) << 3))] = f2bf(a1[r]);
            }
        }
        __syncthreads();
        // ---- stage2: accO += out_w[o, s*64+c] * y2_s
        const unsigned short* wO = out_wbf + (size_t)(wv * 16) * 512 + s * 64;
        const s16x8 wa0 = *(const s16x8*)(wO + (size_t)r16 * 512 + g4 * 8);
        const s16x8 wa1 = *(const s16x8*)(wO + (size_t)r16 * 512 + 32 + g4 * 8);
#pragma unroll
        for (int nt = 0; nt < 7; ++nt) {
            int tv = nt * 16 + r16;
            int v = tv >> 2;
            const s16x8 b0 = *(const s16x8*)&ybuf[tv * 72 + ((g4 * 8) ^ ((v & 7) << 3))];
            const s16x8 b1 = *(const s16x8*)&ybuf[tv * 72 + ((32 + g4 * 8) ^ ((v & 7) << 3))];
            accO[nt] = MFMA16(wa0, b0, accO[nt]);
            accO[nt] = MFMA16(wa1, b1, accO[nt]);
        }
        __syncthreads();
    }

    // ---- epilogue1: y1 = leaky(x + BN(accO)) -> ybuf [tv][o]
#pragma unroll
    for (int nt = 0; nt < 7; ++nt) {
        int tv = nt * 16 + r16;
        int v = tv >> 2, tt = tv & 3;
        if (v < Vn) {
#pragma unroll
            for (int r = 0; r < 4; ++r) {
                int o = wv * 16 + g4 * 4 + r;
                float xv = bf2f(xs[(o * 6 + tt + 1) * 32 + v]);
                float val = (accO[nt][r] + bnp[128 + o]) * bnp[o] + bnp[64 + o];
                float y1 = xv + val;
                y1 = (y1 > 0.f) ? y1 : 0.1f * y1;
                ybuf[(v * 4 + tt) * 72 + (o ^ ((v & 7) << 3))] = f2bf(y1);
            }
        }
    }
    __syncthreads();
    // ---- ff
    f32x4 accF[7];
#pragma unroll
    for (int i = 0; i < 7; ++i) accF[i] = (f32x4){0.f, 0.f, 0.f, 0.f};
    const unsigned short* wF = ff_wbf + (size_t)(wv * 16) * 64;
    const s16x8 fa0 = *(const s16x8*)(wF + (size_t)r16 * 64 + g4 * 8);
    const s16x8 fa1 = *(const s16x8*)(wF + (size_t)r16 * 64 + 32 + g4 * 8);
#pragma unroll
    for (int nt = 0; nt < 7; ++nt) {
        int tv = nt * 16 + r16;
        int v = tv >> 2;
        const s16x8 b0 = *(const s16x8*)&ybuf[tv * 72 + ((g4 * 8) ^ ((v & 7) << 3))];
        const s16x8 b1 = *(const s16x8*)&ybuf[tv * 72 + ((32 + g4 * 8) ^ ((v & 7) << 3))];
        accF[nt] = MFMA16(fa0, b0, accF[nt]);
        accF[nt] = MFMA16(fa1, b1, accF[nt]);
    }
    // ---- epilogue2 + store (t-coalesced)
#pragma unroll
    for (int nt = 0; nt < 7; ++nt) {
        int tv = nt * 16 + r16;
        int v = tv >> 2, tt = tv & 3;
        if (v < Vn) {
#pragma unroll
            for (int r = 0; r < 4; ++r) {
                int o = wv * 16 + g4 * 4 + r;
                float xv = bf2f(xs[(o * 6 + tt + 1) * 32 + v]);
                float val = (accF[nt][r] + bnp[320 + o]) * bnp[192 + o] + bnp[256 + o];
                float y2v = xv + val;
                y2v = (y2v > 0.f) ? y2v : 0.1f * y2v;
                float outv = y2v + xv;
                outv = (outv > 0.f) ? outv : 0.f;
                out[((size_t)(n * Cn + o) * Vn + v) * Tn + t0 + tt] = outv;
            }
        }
    }
}

// ---------------------------------------------------------------------------
extern "C" void kernel_launch(void* const* d_in, const int* in_sizes, int n_in,
                              void* d_out, int out_size, void* d_ws, size_t ws_size,
                              hipStream_t stream) {
    const float* x       = (const float*)d_in[0];
    const float* graph   = (const float*)d_in[1];
    const float* graph_a = (const float*)d_in[2];
    const float* in_w    = (const float*)d_in[3];
    const float* in_b    = (const float*)d_in[4];
    const float* inup_w  = (const float*)d_in[5];
    const float* inup_b  = (const float*)d_in[6];
    const float* diff_w  = (const float*)d_in[7];
    const float* diff_b  = (const float*)d_in[8];
    const float* att0    = (const float*)d_in[9];
    const float* out_w   = (const float*)d_in[10];
    const float* out_b   = (const float*)d_in[11];
    const float* og      = (const float*)d_in[12];
    const float* obeta   = (const float*)d_in[13];
    const float* orm     = (const float*)d_in[14];
    const float* orv     = (const float*)d_in[15];
    const float* ff_w    = (const float*)d_in[16];
    const float* ff_b    = (const float*)d_in[17];
    const float* fg      = (const float*)d_in[18];
    const float* fbeta   = (const float*)d_in[19];
    const float* frm     = (const float*)d_in[20];
    const float* frv     = (const float*)d_in[21];
    float* out = (float*)d_out;

    // ws layout (bytes):
    //   red     @ 0          (65,536)
    //   gate    @ 65,536     (6,144)
    //   attB    @ 71,680     (3,145,728)   bf16 [n][s][32][96]
    //   out_wbf @ 3,217,408  (65,536)
    //   ff_wbf  @ 3,282,944  (8,192)
    //   pq      @ 3,291,136  (13,107,200)
    //   pk      @ 16,398,336 (13,107,200)  total ~29.5 MB
    char* wsb = (char*)d_ws;
    float* red_ws  = (float*)(wsb);
    float* gate_ws = (float*)(wsb + 65536);
    unsigned short* attB = (unsigned short*)(wsb + 71680);
    unsigned short* owb  = (unsigned short*)(wsb + 3217408);
    unsigned short* fwb  = (unsigned short*)(wsb + 3282944);
    __hip_bfloat16* pq = (__hip_bfloat16*)(wsb + 3291136);
    __hip_bfloat16* pk = (__hip_bfloat16*)(wsb + 16398336);

    k_red<<<dim3(Cn, Nn), 64, 0, stream>>>(x, graph_a, red_ws);
    k_gate<<<dim3(Nn), 64, 0, stream>>>(red_ws, diff_w, diff_b, gate_ws);
    k_conv<<<dim3(128), 256, 0, stream>>>(out_w, ff_w, owb, fwb);
    k_proj<<<dim3(Vn, Nn), 256, 0, stream>>>(x, in_w, in_b, inup_w, inup_b, pk, pq);
    k_att3<<<dim3(Sn, Nn), 256, 0, stream>>>(pq, pk, inup_b, graph, att0, gate_ws, attB);
    k_main3<<<dim3(Tn / 4, Nn), 256, 0, stream>>>(x, attB, owb, out_b, og, obeta,
                                                  orm, orv, fwb, ff_b, fg, fbeta,
                                                  frm, frv, out);
}

// Round 5
// 190.331 us; speedup vs baseline: 8.1857x; 1.0557x over previous
//
#include <hip/hip_runtime.h>
#include <hip/hip_bf16.h>
#include <math.h>

#define Nn 64
#define Cn 64
#define Tn 64
#define Vn 25
#define Sn 8
#define ICn 8
#define Wn 3
#define WVn 75

typedef __attribute__((ext_vector_type(8))) short s16x8;   // 8 bf16 (4 VGPR)
typedef __attribute__((ext_vector_type(4))) short s16x4;   // 4 bf16 (2 VGPR)
typedef __attribute__((ext_vector_type(4))) float f32x4;   // MFMA acc

#define MFMA16(a, b, c) __builtin_amdgcn_mfma_f32_16x16x32_bf16(a, b, c, 0, 0, 0)

static __device__ inline unsigned short f2bf(float f) {
    __hip_bfloat16 h = __float2bfloat16(f);
    return *reinterpret_cast<unsigned short*>(&h);
}
static __device__ inline float bf2f(unsigned short u) {
    union { unsigned int i; float f; } x;
    x.i = ((unsigned int)u) << 16;
    return x.f;
}

// ---------------------------------------------------------------------------
// K1: per (n,c) reductions over x rows (collapsed diff/gate branch).
// ---------------------------------------------------------------------------
__global__ __launch_bounds__(64) void k_red(const float* __restrict__ x,
                                            const float* __restrict__ ga,
                                            float* __restrict__ red) {
    const int c = blockIdx.x, n = blockIdx.y;
    const int lane = threadIdx.x;
    float rs = 0.f, r0 = 0.f, r63 = 0.f, xg = 0.f;
    if (lane < Vn) {
        const float* row = x + ((size_t)(n * Cn + c) * Vn + lane) * Tn;
        float g = 0.f;
        for (int j = 0; j < Vn; ++j) g += ga[lane * Vn + j];
        for (int t = 0; t < Tn; ++t) rs += row[t];
        r0 = row[0];
        r63 = row[Tn - 1];
        xg = rs * g;
    }
    for (int off = 32; off > 0; off >>= 1) {
        rs += __shfl_down(rs, off);
        r0 += __shfl_down(r0, off);
        r63 += __shfl_down(r63, off);
        xg += __shfl_down(xg, off);
    }
    if (lane == 0) {
        float* p = red + (size_t)(n * Cn + c) * 4;
        p[0] = rs; p[1] = r0; p[2] = r63; p[3] = xg;
    }
}

// ---------------------------------------------------------------------------
// K1b: gate[n,s,w]
// ---------------------------------------------------------------------------
__global__ __launch_bounds__(64) void k_gate(const float* __restrict__ red,
                                             const float* __restrict__ diff_w,
                                             const float* __restrict__ diff_b,
                                             float* __restrict__ gate) {
    const int n = blockIdx.x;
    const int s = threadIdx.x;
    if (s >= Sn) return;
    float sumd2 = 0.f, rsum = 0.f, rr0 = 0.f, rr63 = 0.f;
    for (int cc = 0; cc < ICn; ++cc) {
        const int oc = s * ICn + cc;
        float a = 0.f;
        for (int c = 0; c < Cn; ++c)
            a += red[(n * Cn + c) * 4 + 3] * diff_w[oc * Cn + c];
        sumd2 += a + 1600.f * diff_b[oc];
        rsum += red[(n * Cn + oc) * 4 + 0];
        rr0  += red[(n * Cn + oc) * 4 + 1];
        rr63 += red[(n * Cn + oc) * 4 + 2];
    }
    const float inv = 1.f / 12800.f;
    float m0 = (sumd2 - (rsum - rr63)) * inv;
    float m1 = (sumd2 - rsum) * inv;
    float m2 = (sumd2 - (rsum - rr0)) * inv;
    float* gp = gate + (n * Sn + s) * Wn;
    gp[0] = 1.f / (1.f + expf(-m0));
    gp[1] = 1.f / (1.f + expf(-m1));
    gp[2] = 1.f / (1.f + expf(-m2));
}

// ---------------------------------------------------------------------------
// K_conv: out_w / ff_w -> bf16
// ---------------------------------------------------------------------------
__global__ __launch_bounds__(256) void k_conv(const float* __restrict__ ow,
                                              const float* __restrict__ fw,
                                              unsigned short* __restrict__ owb,
                                              unsigned short* __restrict__ fwb) {
    int i = blockIdx.x * 256 + threadIdx.x;
    if (i < 64 * 512) owb[i] = f2bf(ow[i]);
    if (i < 64 * 64)  fwb[i] = f2bf(fw[i]);
}

// ---------------------------------------------------------------------------
// K_proj: q/k conv1x1 projections -> bf16 (coalesced along t)
// ---------------------------------------------------------------------------
__global__ __launch_bounds__(256) void k_proj(
    const float* __restrict__ x,
    const float* __restrict__ in_w, const float* __restrict__ in_b,
    const float* __restrict__ inup_w, const float* __restrict__ inup_b,
    __hip_bfloat16* __restrict__ pk, __hip_bfloat16* __restrict__ pq) {
    const int v = blockIdx.x, n = blockIdx.y;
    const int tid = threadIdx.x;
    __shared__ float xs[64 * 65];
    __shared__ float wk[64 * 65];
    __shared__ float wq[64 * 65];

    for (int i = tid; i < 4096; i += 256) {
        int o = i >> 6, c = i & 63;
        wk[o * 65 + c] = in_w[i];
        wq[o * 65 + c] = inup_w[i];
    }
    for (int i = tid; i < 4096; i += 256) {
        int c = i >> 6, t = i & 63;
        xs[c * 65 + t] = x[((size_t)(n * Cn + c) * Vn + v) * Tn + t];
    }
    __syncthreads();

    const int o = tid >> 2, tq = tid & 3;
    float ak[16], aq[16];
#pragma unroll
    for (int t = 0; t < 16; ++t) { ak[t] = 0.f; aq[t] = 0.f; }
    for (int c = 0; c < 64; ++c) {
        float wkc = wk[o * 65 + c], wqc = wq[o * 65 + c];
        const float* xr = &xs[c * 65 + tq * 16];
#pragma unroll
        for (int t = 0; t < 16; ++t) {
            float xv = xr[t];
            ak[t] += wkc * xv;
            aq[t] += wqc * xv;
        }
    }
    const float bk = in_b[o], bq = inup_b[o];
    const size_t base = ((size_t)(n * Cn + o) * Vn + v) * Tn + tq * 16;
#pragma unroll
    for (int t = 0; t < 16; ++t) {
        pk[base + t] = __float2bfloat16(ak[t] + bk);
        pq[base + t] = __float2bfloat16(aq[t] + bq);
    }
}

// ---------------------------------------------------------------------------
// K_att3 (MFMA): fused attention logits + softmax + gate + att0 -> attB.
// (unchanged from R3)
// ---------------------------------------------------------------------------
__global__ __launch_bounds__(256) void k_att3(
    const __hip_bfloat16* __restrict__ pq, const __hip_bfloat16* __restrict__ pk,
    const float* __restrict__ inup_b, const float* __restrict__ graph,
    const float* __restrict__ att0, const float* __restrict__ gate,
    unsigned short* __restrict__ attB) {
    const int s = blockIdx.x, n = blockIdx.y;
    const int tid = threadIdx.x;
    const int lane = tid & 63, wv = tid >> 6;
    const int r16 = lane & 15, g4 = lane >> 4;

    __shared__ unsigned short QS[25 * 536];
    __shared__ unsigned short KS[32 * 512];
    __shared__ float attL[80 * 33];

    for (int i = tid; i < 2048; i += 256) {
        const int tch = i & 7, cc = (i >> 3) & 7, v = i >> 6;
        if (v < Vn) {
            const s16x8 d = *(const s16x8*)(pk +
                (((size_t)(n * Cn + s * ICn + cc) * Vn + v) * Tn + tch * 8));
#pragma unroll
            for (int j = 0; j < 8; ++j)
                KS[v * 512 + ((((tch * 8 + j)) ^ (v & 7)) << 3) + cc] = ((const unsigned short*)&d)[j];
        } else {
#pragma unroll
            for (int j = 0; j < 8; ++j)
                KS[v * 512 + ((((tch * 8 + j)) ^ (v & 7)) << 3) + cc] = 0;
        }
    }
    for (int i = tid; i < 1600; i += 256) {
        const int tch = i & 7, cc = (i >> 3) & 7, uu = i >> 6;
        const s16x8 d = *(const s16x8*)(pq +
            (((size_t)(n * Cn + s * ICn + cc) * Vn + uu) * Tn + tch * 8));
#pragma unroll
        for (int j = 0; j < 8; ++j)
            QS[uu * 536 + (tch * 8 + j + 1) * 8 + cc] = ((const unsigned short*)&d)[j];
    }
    if (tid < 200) {
        const int uu = tid >> 3, cc = tid & 7;
        const unsigned short b = f2bf(inup_b[s * ICn + cc]);
        QS[uu * 536 + 0 * 8 + cc] = b;
        QS[uu * 536 + 65 * 8 + cc] = b;
    }
    __syncthreads();

    for (int tile = wv; tile < 10; tile += 4) {
        const int mt = tile >> 1, nt = tile & 1;
        const int u = mt * 16 + r16;
        const int w = u / 25, uu = u % 25;
        const int v = nt * 16 + r16;
        const unsigned short* qbase = &QS[uu * 536 + (g4 + w) * 8];
        const unsigned short* kbase = &KS[v * 512];
        f32x4 acc = (f32x4){0.f, 0.f, 0.f, 0.f};
#pragma unroll
        for (int kb = 0; kb < 16; ++kb) {
            const s16x8 af = *(const s16x8*)(qbase + kb * 32);
            const s16x8 bf = *(const s16x8*)(kbase + (((kb * 4 + g4) ^ (v & 7)) << 3));
            acc = MFMA16(af, bf, acc);
        }
#pragma unroll
        for (int r = 0; r < 4; ++r)
            attL[(mt * 16 + g4 * 4 + r) * 33 + v] = acc[r];
    }
    __syncthreads();

    if (tid < WVn) {
        const int u = tid, u0 = u % Vn;
        const float* gr = graph + (s * Vn + u0) * Vn;
        float av[Vn];
        float mx = -1e30f;
#pragma unroll
        for (int v = 0; v < Vn; ++v) {
            float a = attL[u * 33 + v] * (1.f / 512.f);
            av[v] = (gr[v] > 0.f) ? a : -1e30f;
            mx = fmaxf(mx, av[v]);
        }
        float ssum = 0.f;
#pragma unroll
        for (int v = 0; v < Vn; ++v) {
            float e = (av[v] > -1e29f) ? expf(av[v] - mx) : 0.f;
            av[v] = e;
            ssum += e;
        }
        const float g = gate[(n * Sn + s) * Wn + (u % Wn)];
        const float sc = g / ssum;
        const float* a0 = att0 + (s * WVn + u) * Vn;
#pragma unroll
        for (int v = 0; v < Vn; ++v) attL[u * 33 + v] = av[v] * sc + a0[v];
    }
    __syncthreads();

    unsigned short* ab = attB + ((size_t)(n * Sn + s)) * 32 * 96;
    for (int i = tid; i < 32 * 96; i += 256) {
        const int v = i / 96, kk = i % 96;
        const int w2 = kk >> 5, vp = kk & 31;
        float val = (v < Vn && vp < Vn) ? attL[(w2 * Vn + vp) * 33 + v] : 0.f;
        ab[i] = f2bf(val);
    }
}

// ---------------------------------------------------------------------------
// K_main4 (MFMA, barrier-free s-loop): per (tc=8t, n) block, 4 waves.
// Wave wv owns 2 t's (tl 0/1 -> global t = t0 + wv*2 + tl). The full chain
//   stage1 (y2 for all 64 c at own t's) -> stage2 (out-proj) -> epi1 -> ff
// is wave-private: y2/y1 round-trip through a per-wave LDS slab, so the
// s-loop needs NO __syncthreads (per-wave lgkmcnt only). 1 barrier/block.
//   stage1: M=(tl*64+c) 8 tiles, K=96 (attB w-blocks), N=32(v). C rows are
//           c-consecutive -> packed ds_write_b64 into yw[col=(tl,v)][c^swz].
//   stage2: M=o 4 tiles, N=col 4 tiles, K=c (2 steps); acc across s.
//   epi1:   y1 = leaky(x+BN) -> yw[col][o^swz];  ff: K=o;  epi2 -> out.
// xs banking: v-chunk XOR by (c&3) breaks the 640B c-stride 16-way conflict.
// ---------------------------------------------------------------------------
__global__ __launch_bounds__(256, 2) void k_main4(
    const float* __restrict__ x, const unsigned short* __restrict__ attB,
    const unsigned short* __restrict__ out_wbf, const float* __restrict__ out_b,
    const float* __restrict__ og, const float* __restrict__ obeta,
    const float* __restrict__ orm, const float* __restrict__ orv,
    const unsigned short* __restrict__ ff_wbf, const float* __restrict__ ff_b,
    const float* __restrict__ fg, const float* __restrict__ fbeta,
    const float* __restrict__ frm, const float* __restrict__ frv,
    float* __restrict__ out) {
    const int tc = blockIdx.x, n = blockIdx.y;
    const int t0 = tc * 8;
    const int tid = threadIdx.x;
    const int lane = tid & 63, wv = tid >> 6;
    const int r16 = lane & 15, g4 = lane >> 4;

    __shared__ unsigned short xs[64 * 10 * 32];   // [c][tau 0..9][v-chunk swz] 40KB
    __shared__ unsigned short yw[4 * 64 * 72];    // per-wave [col 64][c 64 ^swz] 36KB
    __shared__ float bnp[384];

    if (tid < 64) {
        int o = tid;
        float so = og[o] * rsqrtf(orv[o] + 1e-5f);
        bnp[o] = so; bnp[64 + o] = obeta[o] - orm[o] * so; bnp[128 + o] = out_b[o];
        float sf = fg[o] * rsqrtf(frv[o] + 1e-5f);
        bnp[192 + o] = sf; bnp[256 + o] = fbeta[o] - frm[o] * sf; bnp[320 + o] = ff_b[o];
    }
    for (int p = tid; p < 64 * 32; p += 256) {
        int c = p >> 5, v = p & 31;
        const float* xr = x + ((size_t)(n * Cn + c) * Vn + (v < Vn ? v : 0)) * Tn;
        const int sv = (((v >> 3) ^ (c & 3)) << 3) + (v & 7);
#pragma unroll
        for (int tau = 0; tau < 10; ++tau) {
            int tg = t0 - 1 + tau;
            float val = (v < Vn && tg >= 0 && tg < Tn) ? xr[tg] : 0.f;
            xs[(c * 10 + tau) * 32 + sv] = f2bf(val);
        }
    }
    __syncthreads();   // the ONLY barrier

    unsigned short* myw = yw + wv * (64 * 72);
    const int achunk = (g4 ^ (r16 & 3)) << 3;  // xs read chunk (c&3 == r16&3)

    f32x4 accO[4][4];
#pragma unroll
    for (int i = 0; i < 4; ++i)
#pragma unroll
        for (int j = 0; j < 4; ++j) accO[i][j] = (f32x4){0.f, 0.f, 0.f, 0.f};

    for (int s = 0; s < Sn; ++s) {
        // ---- stage1: y2[(tl,c)][v] for this wave's 2 t's
        const unsigned short* aB = attB + ((size_t)(n * Sn + s)) * 32 * 96;
        s16x8 bfr[3][2];
#pragma unroll
        for (int k = 0; k < 3; ++k)
#pragma unroll
            for (int nt = 0; nt < 2; ++nt)
                bfr[k][nt] = *(const s16x8*)(aB + (nt * 16 + r16) * 96 + k * 32 + g4 * 8);
#pragma unroll
        for (int m = 0; m < 8; ++m) {
            const int tl = m >> 2;
            const int ca = (m & 3) * 16 + r16;
            const unsigned short* abase = &xs[(ca * 10 + wv * 2 + tl) * 32 + achunk];
            f32x4 c0 = (f32x4){0.f, 0.f, 0.f, 0.f};
            f32x4 c1 = (f32x4){0.f, 0.f, 0.f, 0.f};
#pragma unroll
            for (int kb = 0; kb < 3; ++kb) {
                const s16x8 af = *(const s16x8*)(abase + kb * 32);
                c0 = MFMA16(af, bfr[kb][0], c0);
                c1 = MFMA16(af, bfr[kb][1], c1);
            }
            const int cw = (m & 3) * 16 + g4 * 4;
            const int col0 = tl * 32 + r16;       // nt=0
            const int col1 = tl * 32 + 16 + r16;  // nt=1
            s16x4 p0, p1;
#pragma unroll
            for (int r = 0; r < 4; ++r) { p0[r] = f2bf(c0[r]); p1[r] = f2bf(c1[r]); }
            *(s16x4*)&myw[col0 * 72 + (cw ^ ((col0 & 7) << 3))] = p0;
            *(s16x4*)&myw[col1 * 72 + (cw ^ ((col1 & 7) << 3))] = p1;
        }
        // ---- stage2: accO[o][col] += out_w[o, s*64+c] * y2  (wave-private read)
        s16x8 wa[4][2];
#pragma unroll
        for (int ma = 0; ma < 4; ++ma)
#pragma unroll
            for (int kb = 0; kb < 2; ++kb)
                wa[ma][kb] = *(const s16x8*)(out_wbf +
                    (size_t)(ma * 16 + r16) * 512 + s * 64 + kb * 32 + g4 * 8);
#pragma unroll
        for (int na = 0; na < 4; ++na) {
            const int col = na * 16 + r16;
            const s16x8 b0 = *(const s16x8*)&myw[col * 72 + ((g4 * 8) ^ ((col & 7) << 3))];
            const s16x8 b1 = *(const s16x8*)&myw[col * 72 + ((32 + g4 * 8) ^ ((col & 7) << 3))];
#pragma unroll
            for (int ma = 0; ma < 4; ++ma) {
                accO[ma][na] = MFMA16(wa[ma][0], b0, accO[ma][na]);
                accO[ma][na] = MFMA16(wa[ma][1], b1, accO[ma][na]);
            }
        }
    }

    // ---- epilogue1: y1 = leaky(x + BN(accO)) -> myw[col][o^swz]
#pragma unroll
    for (int ma = 0; ma < 4; ++ma) {
#pragma unroll
        for (int na = 0; na < 4; ++na) {
            const int col = na * 16 + r16;
            const int tl = col >> 5, v = col & 31;
            const int ob = ma * 16 + g4 * 4;
            s16x4 pk_;
#pragma unroll
            for (int r = 0; r < 4; ++r) {
                const int o = ob + r;
                const float xv = bf2f(xs[(o * 10 + wv * 2 + tl + 1) * 32 +
                                         (((v >> 3) ^ (o & 3)) << 3) + (v & 7)]);
                float val = (accO[ma][na][r] + bnp[128 + o]) * bnp[o] + bnp[64 + o];
                float y1 = xv + val;
                y1 = (y1 > 0.f) ? y1 : 0.1f * y1;
                pk_[r] = f2bf(y1);
            }
            *(s16x4*)&myw[col * 72 + (ob ^ ((col & 7) << 3))] = pk_;
        }
    }
    // ---- ff (wave-private): accF[o'][col] = ff_w[o'][o] * y1
    f32x4 accF[4][4];
#pragma unroll
    for (int i = 0; i < 4; ++i)
#pragma unroll
        for (int j = 0; j < 4; ++j) accF[i][j] = (f32x4){0.f, 0.f, 0.f, 0.f};
    s16x8 fa[4][2];
#pragma unroll
    for (int ma = 0; ma < 4; ++ma)
#pragma unroll
        for (int kb = 0; kb < 2; ++kb)
            fa[ma][kb] = *(const s16x8*)(ff_wbf +
                (size_t)(ma * 16 + r16) * 64 + kb * 32 + g4 * 8);
#pragma unroll
    for (int na = 0; na < 4; ++na) {
        const int col = na * 16 + r16;
        const s16x8 b0 = *(const s16x8*)&myw[col * 72 + ((g4 * 8) ^ ((col & 7) << 3))];
        const s16x8 b1 = *(const s16x8*)&myw[col * 72 + ((32 + g4 * 8) ^ ((col & 7) << 3))];
#pragma unroll
        for (int ma = 0; ma < 4; ++ma) {
            accF[ma][na] = MFMA16(fa[ma][0], b0, accF[ma][na]);
            accF[ma][na] = MFMA16(fa[ma][1], b1, accF[ma][na]);
        }
    }
    // ---- epilogue2 + store
#pragma unroll
    for (int ma = 0; ma < 4; ++ma) {
#pragma unroll
        for (int na = 0; na < 4; ++na) {
            const int col = na * 16 + r16;
            const int tl = col >> 5, v = col & 31;
            if (v < Vn) {
                const int tt = t0 + wv * 2 + tl;
                const int ob = ma * 16 + g4 * 4;
#pragma unroll
                for (int r = 0; r < 4; ++r) {
                    const int o = ob + r;
                    const float xv = bf2f(xs[(o * 10 + wv * 2 + tl + 1) * 32 +
                                             (((v >> 3) ^ (o & 3)) << 3) + (v & 7)]);
                    float val = (accF[ma][na][r] + bnp[320 + o]) * bnp[192 + o] + bnp[256 + o];
                    float y2v = xv + val;
                    y2v = (y2v > 0.f) ? y2v : 0.1f * y2v;
                    float outv = y2v + xv;
                    outv = (outv > 0.f) ? outv : 0.f;
                    out[((size_t)(n * Cn + o) * Vn + v) * Tn + tt] = outv;
                }
            }
        }
    }
}

// ---------------------------------------------------------------------------
extern "C" void kernel_launch(void* const* d_in, const int* in_sizes, int n_in,
                              void* d_out, int out_size, void* d_ws, size_t ws_size,
                              hipStream_t stream) {
    const float* x       = (const float*)d_in[0];
    const float* graph   = (const float*)d_in[1];
    const float* graph_a = (const float*)d_in[2];
    const float* in_w    = (const float*)d_in[3];
    const float* in_b    = (const float*)d_in[4];
    const float* inup_w  = (const float*)d_in[5];
    const float* inup_b  = (const float*)d_in[6];
    const float* diff_w  = (const float*)d_in[7];
    const float* diff_b  = (const float*)d_in[8];
    const float* att0    = (const float*)d_in[9];
    const float* out_w   = (const float*)d_in[10];
    const float* out_b   = (const float*)d_in[11];
    const float* og      = (const float*)d_in[12];
    const float* obeta   = (const float*)d_in[13];
    const float* orm     = (const float*)d_in[14];
    const float* orv     = (const float*)d_in[15];
    const float* ff_w    = (const float*)d_in[16];
    const float* ff_b    = (const float*)d_in[17];
    const float* fg      = (const float*)d_in[18];
    const float* fbeta   = (const float*)d_in[19];
    const float* frm     = (const float*)d_in[20];
    const float* frv     = (const float*)d_in[21];
    float* out = (float*)d_out;

    // ws layout (bytes): red@0 (64K) | gate@65,536 | attB@71,680 (3M)
    //   out_wbf@3,217,408 | ff_wbf@3,282,944 | pq@3,291,136 | pk@16,398,336
    char* wsb = (char*)d_ws;
    float* red_ws  = (float*)(wsb);
    float* gate_ws = (float*)(wsb + 65536);
    unsigned short* attB = (unsigned short*)(wsb + 71680);
    unsigned short* owb  = (unsigned short*)(wsb + 3217408);
    unsigned short* fwb  = (unsigned short*)(wsb + 3282944);
    __hip_bfloat16* pq = (__hip_bfloat16*)(wsb + 3291136);
    __hip_bfloat16* pk = (__hip_bfloat16*)(wsb + 16398336);

    k_red<<<dim3(Cn, Nn), 64, 0, stream>>>(x, graph_a, red_ws);
    k_gate<<<dim3(Nn), 64, 0, stream>>>(red_ws, diff_w, diff_b, gate_ws);
    k_conv<<<dim3(128), 256, 0, stream>>>(out_w, ff_w, owb, fwb);
    k_proj<<<dim3(Vn, Nn), 256, 0, stream>>>(x, in_w, in_b, inup_w, inup_b, pk, pq);
    k_att3<<<dim3(Sn, Nn), 256, 0, stream>>>(pq, pk, inup_b, graph, att0, gate_ws, attB);
    k_main4<<<dim3(Tn / 8, Nn), 256, 0, stream>>>(x, attB, owb, out_b, og, obeta,
                                                  orm, orv, fwb, ff_b, fg, fbeta,
                                                  frm, frv, out);
}